// Round 2
// baseline (2663.225 us; speedup 1.0000x reference)
//
#include <hip/hip_runtime.h>

#define EPS 1e-3f

// Tensor geometry (fixed for this problem):
// L1 out (y1): (2,16,21,256,256)  m1: (2,21,256,256)
// L2 out (h2): (2,32,11,128,128)  m2: (2,11,128,128)
// L3 out (h3): (2,64,5,64,64)     m3: (2,5,64,64)
// L4 out:      (2,64,2,64,64) -> d_out (2,128,64,64) same layout

// ---------------- Layer 1: voxel scatter into pre-activation accumulator ----------------
__global__ __launch_bounds__(256) void scatter_l1(
    const float* __restrict__ vf, const int* __restrict__ coors, int NV,
    const float* __restrict__ w1, float* __restrict__ y1, float* __restrict__ m1)
{
    __shared__ float ws[16 * 3 * 27];  // (oc, c, tap)
    for (int e = threadIdx.x; e < 16 * 3 * 27; e += 256) ws[e] = w1[e];
    __syncthreads();

    int i = blockIdx.x * 256 + threadIdx.x;
    if (i >= NV) return;

    const int b = coors[4 * i + 0];
    const int z = coors[4 * i + 1];
    const int y = coors[4 * i + 2];
    const int x = coors[4 * i + 3];
    const float f0 = vf[3 * i + 0];
    const float f1 = vf[3 * i + 1];
    const float f2 = vf[3 * i + 2];

    // input idx = 2*o + k - 1  ->  for each k, o = (coord+1-k)/2 when even & in range
    int ozv[2], kzv[2], nz = 0;
    int oyv[2], kyv[2], ny = 0;
    int oxv[2], kxv[2], nx = 0;
#pragma unroll
    for (int k = 0; k < 3; ++k) {
        int t = z + 1 - k;
        if (t >= 0 && !(t & 1)) { int o = t >> 1; if (o < 21) { ozv[nz] = o; kzv[nz] = k; ++nz; } }
    }
#pragma unroll
    for (int k = 0; k < 3; ++k) {
        int t = y + 1 - k;
        if (t >= 0 && !(t & 1)) { int o = t >> 1; if (o < 256) { oyv[ny] = o; kyv[ny] = k; ++ny; } }
    }
#pragma unroll
    for (int k = 0; k < 3; ++k) {
        int t = x + 1 - k;
        if (t >= 0 && !(t & 1)) { int o = t >> 1; if (o < 256) { oxv[nx] = o; kxv[nx] = k; ++nx; } }
    }

    for (int a = 0; a < nz; ++a)
        for (int bb = 0; bb < ny; ++bb)
            for (int c = 0; c < nx; ++c) {
                const int oz = ozv[a], oy = oyv[bb], ox = oxv[c];
                const int tap = (kzv[a] * 3 + kyv[bb]) * 3 + kxv[c];
                const int sp = ((b * 21 + oz) * 256 + oy) * 256 + ox;
                m1[sp] = 1.0f;
                const int base = (b * 16) * 1376256 + oz * 65536 + oy * 256 + ox;
#pragma unroll
                for (int oc = 0; oc < 16; ++oc) {
                    const float s = ws[oc * 81 + tap] * f0 + ws[oc * 81 + 27 + tap] * f1 +
                                    ws[oc * 81 + 54 + tap] * f2;
                    atomicAdd(&y1[base + oc * 1376256], s);
                }
            }
}

// ---------------- Layer 2: dense conv 16->32, k3, s2, pad(1,1,1) ----------------
// input virtual h1 = relu(y1*scale1+shift1)*m1 applied during staging.
// Tap-outer / oc-inner ordering keeps live set = acc[32] + 1 tap value (no v[27] array).
__global__ __launch_bounds__(256, 4) void conv_l2(
    const float* __restrict__ y1, const float* __restrict__ m1,
    const float* __restrict__ w2,
    const float* __restrict__ g1, const float* __restrict__ bb1,
    const float* __restrict__ rm1, const float* __restrict__ rv1,
    const float* __restrict__ g2, const float* __restrict__ bb2,
    const float* __restrict__ rm2, const float* __restrict__ rv2,
    float* __restrict__ h2, float* __restrict__ m2)
{
    __shared__ float sIn[3 * 17 * 65];
    __shared__ float sM[3 * 17 * 65];
    const int tid = threadIdx.x;
    const int tx = tid & 31, ty = tid >> 5;             // 32 x 8 spatial tile
    const int ox0 = blockIdx.x * 32, oy0 = blockIdx.y * 8;
    const int bz = blockIdx.z;
    const int b = bz / 11, oz = bz % 11;
    const int iz0 = 2 * oz - 1, iy0 = 2 * oy0 - 1, ix0 = 2 * ox0 - 1;

    // stage mask tile once
    for (int e = tid; e < 3 * 17 * 65; e += 256) {
        const int ez = e / (17 * 65), r = e % (17 * 65), ey = r / 65, ex = r % 65;
        const int iz = iz0 + ez, iy = iy0 + ey, ix = ix0 + ex;
        float mv = 0.f;
        if ((unsigned)iz < 21u && (unsigned)iy < 256u && (unsigned)ix < 256u)
            mv = m1[((b * 21 + iz) * 256 + iy) * 256 + ix];
        sM[e] = mv;
    }
    __syncthreads();

    float msum = 0.f;
#pragma unroll
    for (int kz = 0; kz < 3; ++kz)
#pragma unroll
        for (int ky = 0; ky < 3; ++ky)
#pragma unroll
            for (int kx = 0; kx < 3; ++kx)
                msum += sM[(kz * 17 + 2 * ty + ky) * 65 + 2 * tx + kx];
    const float mout = msum > 0.f ? 1.f : 0.f;

    float acc[32];
#pragma unroll
    for (int oc = 0; oc < 32; ++oc) acc[oc] = 0.f;

#pragma unroll 1
    for (int cin = 0; cin < 16; ++cin) {
        const float inv = g1[cin] * rsqrtf(rv1[cin] + EPS);
        const float sh = bb1[cin] - rm1[cin] * inv;
        for (int e = tid; e < 3 * 17 * 65; e += 256) {
            const int ez = e / (17 * 65), r = e % (17 * 65), ey = r / 65, ex = r % 65;
            const int iz = iz0 + ez, iy = iy0 + ey, ix = ix0 + ex;
            float v = 0.f;
            if ((unsigned)iz < 21u && (unsigned)iy < 256u && (unsigned)ix < 256u) {
                const float yv = y1[(((b * 16 + cin) * 21 + iz) * 256 + iy) * 256 + ix];
                v = fmaxf(yv * inv + sh, 0.f) * sM[e];
            }
            sIn[e] = v;
        }
        __syncthreads();

        const float* wb = w2 + cin * 27;   // + oc*16*27 + tap
#pragma unroll
        for (int kz = 0; kz < 3; ++kz)
#pragma unroll
            for (int ky = 0; ky < 3; ++ky)
#pragma unroll
                for (int kx = 0; kx < 3; ++kx) {
                    const int tap = (kz * 3 + ky) * 3 + kx;
                    const float vt = sIn[(kz * 17 + 2 * ty + ky) * 65 + 2 * tx + kx];
#pragma unroll
                    for (int oc = 0; oc < 32; ++oc)
                        acc[oc] = fmaf(wb[oc * 432 + tap], vt, acc[oc]);
                }
        __syncthreads();
    }

    const int oy = oy0 + ty, ox = ox0 + tx;
    m2[((b * 11 + oz) * 128 + oy) * 128 + ox] = mout;
#pragma unroll
    for (int oc = 0; oc < 32; ++oc) {
        const float inv2 = g2[oc] * rsqrtf(rv2[oc] + EPS);
        const float sh2 = bb2[oc] - rm2[oc] * inv2;
        h2[(((b * 32 + oc) * 11 + oz) * 128 + oy) * 128 + ox] =
            fmaxf(acc[oc] * inv2 + sh2, 0.f) * mout;
    }
}

// ---------------- Layer 3: dense conv 32->64, k3, s2, pad(0,1,1) ----------------
// 16x8 spatial tile, 256 threads = 128 pixel-threads x 2 oc-halves (all 64 oc per block).
__global__ __launch_bounds__(256, 4) void conv_l3(
    const float* __restrict__ h2, const float* __restrict__ m2,
    const float* __restrict__ w3,
    const float* __restrict__ g3, const float* __restrict__ bb3,
    const float* __restrict__ rm3, const float* __restrict__ rv3,
    float* __restrict__ h3, float* __restrict__ m3)
{
    __shared__ float sIn[3 * 17 * 33];
    __shared__ float sM[3 * 17 * 33];
    const int tid = threadIdx.x;
    const int tx = tid & 15, ty = (tid >> 4) & 7, half = tid >> 7;
    const int ox0 = blockIdx.x * 16, oy0 = blockIdx.y * 8;
    const int bz = blockIdx.z;
    const int b = bz / 5, oz = bz % 5;
    const int iz0 = 2 * oz, iy0 = 2 * oy0 - 1, ix0 = 2 * ox0 - 1;  // z pad 0

    for (int e = tid; e < 3 * 17 * 33; e += 256) {
        const int ez = e / (17 * 33), rr = e % (17 * 33), ey = rr / 33, ex = rr % 33;
        const int iz = iz0 + ez, iy = iy0 + ey, ix = ix0 + ex;
        float mv = 0.f;
        if ((unsigned)iy < 128u && (unsigned)ix < 128u)  // iz always in [0,10]
            mv = m2[((b * 11 + iz) * 128 + iy) * 128 + ix];
        sM[e] = mv;
    }
    __syncthreads();

    float msum = 0.f;
#pragma unroll
    for (int kz = 0; kz < 3; ++kz)
#pragma unroll
        for (int ky = 0; ky < 3; ++ky)
#pragma unroll
            for (int kx = 0; kx < 3; ++kx)
                msum += sM[(kz * 17 + 2 * ty + ky) * 33 + 2 * tx + kx];
    const float mout = msum > 0.f ? 1.f : 0.f;

    float acc[32];
#pragma unroll
    for (int oc = 0; oc < 32; ++oc) acc[oc] = 0.f;

#pragma unroll 1
    for (int cin = 0; cin < 32; ++cin) {
        for (int e = tid; e < 3 * 17 * 33; e += 256) {
            const int ez = e / (17 * 33), rr = e % (17 * 33), ey = rr / 33, ex = rr % 33;
            const int iz = iz0 + ez, iy = iy0 + ey, ix = ix0 + ex;
            float v = 0.f;
            if ((unsigned)iy < 128u && (unsigned)ix < 128u)
                v = h2[(((b * 32 + cin) * 11 + iz) * 128 + iy) * 128 + ix];
            sIn[e] = v;
        }
        __syncthreads();

        const float* wb = w3 + (half * 32 * 32 + cin) * 27;  // + ocLocal*32*27 + tap
#pragma unroll
        for (int kz = 0; kz < 3; ++kz)
#pragma unroll
            for (int ky = 0; ky < 3; ++ky)
#pragma unroll
                for (int kx = 0; kx < 3; ++kx) {
                    const int tap = (kz * 3 + ky) * 3 + kx;
                    const float vt = sIn[(kz * 17 + 2 * ty + ky) * 33 + 2 * tx + kx];
#pragma unroll
                    for (int oc = 0; oc < 32; ++oc)
                        acc[oc] = fmaf(wb[oc * 864 + tap], vt, acc[oc]);
                }
        __syncthreads();
    }

    const int oy = oy0 + ty, ox = ox0 + tx;
    if (half == 0) m3[(b * 5 + oz) * 4096 + oy * 64 + ox] = mout;
#pragma unroll
    for (int oc = 0; oc < 32; ++oc) {
        const int ocg = half * 32 + oc;
        const float inv = g3[ocg] * rsqrtf(rv3[ocg] + EPS);
        const float sh = bb3[ocg] - rm3[ocg] * inv;
        h3[(((b * 64 + ocg) * 5 + oz) * 64 + oy) * 64 + ox] =
            fmaxf(acc[oc] * inv + sh, 0.f) * mout;
    }
}

// ---------------- Layer 4: conv 64->64, k(3,1,1), s(2,1,1), pad 0 ----------------
// oc split across blockIdx.y so each thread holds only acc[32].
__global__ __launch_bounds__(256, 4) void conv_l4(
    const float* __restrict__ h3, const float* __restrict__ m3,
    const float* __restrict__ w4,
    const float* __restrict__ g4, const float* __restrict__ bb4,
    const float* __restrict__ rm4, const float* __restrict__ rv4,
    float* __restrict__ out)
{
    const int p = blockIdx.x * 256 + threadIdx.x;  // 0..4095 spatial
    const int bo = blockIdx.y;
    const int b = bo >> 2, od = (bo >> 1) & 1, half = bo & 1;

    const float msum = m3[(b * 5 + 2 * od + 0) * 4096 + p] +
                       m3[(b * 5 + 2 * od + 1) * 4096 + p] +
                       m3[(b * 5 + 2 * od + 2) * 4096 + p];
    const float mout = msum > 0.f ? 1.f : 0.f;

    float acc[32];
#pragma unroll
    for (int oc = 0; oc < 32; ++oc) acc[oc] = 0.f;

#pragma unroll 1
    for (int c = 0; c < 64; ++c) {
        const float v0 = h3[((b * 64 + c) * 5 + 2 * od + 0) * 4096 + p];
        const float v1 = h3[((b * 64 + c) * 5 + 2 * od + 1) * 4096 + p];
        const float v2 = h3[((b * 64 + c) * 5 + 2 * od + 2) * 4096 + p];
        const float* wp = w4 + ((half * 32) * 64 + c) * 3;
#pragma unroll
        for (int oc = 0; oc < 32; ++oc) {
            acc[oc] = fmaf(wp[oc * 192 + 0], v0,
                      fmaf(wp[oc * 192 + 1], v1,
                      fmaf(wp[oc * 192 + 2], v2, acc[oc])));
        }
    }

#pragma unroll
    for (int oc = 0; oc < 32; ++oc) {
        const int ocg = half * 32 + oc;
        const float inv = g4[ocg] * rsqrtf(rv4[ocg] + EPS);
        const float sh = bb4[ocg] - rm4[ocg] * inv;
        out[((b * 64 + ocg) * 2 + od) * 4096 + p] = fmaxf(acc[oc] * inv + sh, 0.f) * mout;
    }
}

extern "C" void kernel_launch(void* const* d_in, const int* in_sizes, int n_in,
                              void* d_out, int out_size, void* d_ws, size_t ws_size,
                              hipStream_t stream)
{
    const float* vf    = (const float*)d_in[0];
    const int*   coors = (const int*)d_in[1];
    // d_in[2] = batch_size (==2, hardcoded in geometry)
    const float* w1 = (const float*)d_in[3];
    const float* g1 = (const float*)d_in[4];
    const float* b1 = (const float*)d_in[5];
    const float* rm1 = (const float*)d_in[6];
    const float* rv1 = (const float*)d_in[7];
    const float* w2 = (const float*)d_in[8];
    const float* g2 = (const float*)d_in[9];
    const float* b2 = (const float*)d_in[10];
    const float* rm2 = (const float*)d_in[11];
    const float* rv2 = (const float*)d_in[12];
    const float* w3 = (const float*)d_in[13];
    const float* g3 = (const float*)d_in[14];
    const float* b3 = (const float*)d_in[15];
    const float* rm3 = (const float*)d_in[16];
    const float* rv3 = (const float*)d_in[17];
    const float* w4 = (const float*)d_in[18];
    const float* g4 = (const float*)d_in[19];
    const float* b4 = (const float*)d_in[20];
    const float* rm4 = (const float*)d_in[21];
    const float* rv4 = (const float*)d_in[22];

    const int NV = in_sizes[0] / 3;

    float* ws = (float*)d_ws;
    float* y1 = ws;                    // 44,040,192 f  (2,16,21,256,256)
    float* m1 = y1 + 44040192;         //  2,752,512 f  (2,21,256,256)
    float* h2 = m1 + 2752512;          // 11,534,336 f  (2,32,11,128,128)
    float* m2 = h2 + 11534336;         //    360,448 f  (2,11,128,128)
    float* h3 = m2 + 360448;           //  2,621,440 f  (2,64,5,64,64)
    float* m3 = h3 + 2621440;          //     40,960 f  (2,5,64,64)

    // zero the scatter accumulator + mask (y1 and m1 are contiguous)
    hipMemsetAsync(y1, 0, (size_t)(44040192 + 2752512) * sizeof(float), stream);

    scatter_l1<<<(NV + 255) / 256, 256, 0, stream>>>(vf, coors, NV, w1, y1, m1);
    conv_l2<<<dim3(4, 16, 22), 256, 0, stream>>>(y1, m1, w2, g1, b1, rm1, rv1,
                                                 g2, b2, rm2, rv2, h2, m2);
    conv_l3<<<dim3(4, 8, 10), 256, 0, stream>>>(h2, m2, w3, g3, b3, rm3, rv3, h3, m3);
    conv_l4<<<dim3(16, 8), 256, 0, stream>>>(h3, m3, w4, g4, b4, rm4, rv4, (float*)d_out);
}

// Round 3
// 992.934 us; speedup vs baseline: 2.6822x; 2.6822x over previous
//
#include <hip/hip_runtime.h>

#define EPS 1e-3f

// Tensor geometry (fixed for this problem):
// L1 out (y1): (2,16,21,256,256)  m1: (2,21,256,256)
// L2 out (h2): (2,32,11,128,128)  m2: (2,11,128,128)
// L3 out (h3): (2,64,5,64,64)     m3: (2,5,64,64)
// L4 out:      (2,64,2,64,64) -> d_out (2,128,64,64) same layout
//
// Weights are repacked to (cin, tap, oc) with BN scale folded in, so conv
// kernels read them through BLOCK-uniform pointers -> scalar s_load_dwordx16.
// Per-thread accumulators capped at 16 to stay well under a 64-VGPR budget
// (round-2 lesson: compiler targets high occupancy and spills big acc arrays).

// ---------------- Weight repack + BN fold ----------------
__global__ __launch_bounds__(256) void repack(
    const float* __restrict__ w2, const float* __restrict__ g2, const float* __restrict__ b2,
    const float* __restrict__ rm2, const float* __restrict__ rv2,
    const float* __restrict__ w3, const float* __restrict__ g3, const float* __restrict__ b3,
    const float* __restrict__ rm3, const float* __restrict__ rv3,
    const float* __restrict__ w4, const float* __restrict__ g4, const float* __restrict__ b4,
    const float* __restrict__ rm4, const float* __restrict__ rv4,
    float* __restrict__ wT2, float* __restrict__ wT3, float* __restrict__ wT4,
    float* __restrict__ shb)
{
    const int i = blockIdx.x * 256 + threadIdx.x;
    if (i < 13824) {                       // wT2[(cin*27+tap)*32+oc], 16x27x32
        const int cin = i / 864, tap = (i / 32) % 27, oc = i & 31;
        const float inv = g2[oc] * rsqrtf(rv2[oc] + EPS);
        wT2[i] = w2[(oc * 16 + cin) * 27 + tap] * inv;
    } else if (i < 69120) {                // wT3[(cin*27+tap)*64+oc], 32x27x64
        const int j = i - 13824;
        const int cin = j / 1728, tap = (j / 64) % 27, oc = j & 63;
        const float inv = g3[oc] * rsqrtf(rv3[oc] + EPS);
        wT3[j] = w3[(oc * 32 + cin) * 27 + tap] * inv;
    } else if (i < 81408) {                // wT4[(c*3+kz)*64+oc], 64x3x64
        const int j = i - 69120;
        const int c = j / 192, kz = (j / 64) % 3, oc = j & 63;
        const float inv = g4[oc] * rsqrtf(rv4[oc] + EPS);
        wT4[j] = w4[(oc * 64 + c) * 3 + kz] * inv;
    } else if (i < 81568) {                // shifts: sh2[32], sh3[64], sh4[64]
        const int j = i - 81408;
        if (j < 32) {
            const float inv = g2[j] * rsqrtf(rv2[j] + EPS);
            shb[j] = b2[j] - rm2[j] * inv;
        } else if (j < 96) {
            const int o = j - 32;
            const float inv = g3[o] * rsqrtf(rv3[o] + EPS);
            shb[j] = b3[o] - rm3[o] * inv;
        } else {
            const int o = j - 96;
            const float inv = g4[o] * rsqrtf(rv4[o] + EPS);
            shb[j] = b4[o] - rm4[o] * inv;
        }
    }
}

// ---------------- Layer 1: voxel scatter into pre-activation accumulator ----------------
__global__ __launch_bounds__(256) void scatter_l1(
    const float* __restrict__ vf, const int* __restrict__ coors, int NV,
    const float* __restrict__ w1, float* __restrict__ y1, float* __restrict__ m1)
{
    __shared__ float ws[16 * 3 * 27];  // (oc, c, tap)
    for (int e = threadIdx.x; e < 16 * 3 * 27; e += 256) ws[e] = w1[e];
    __syncthreads();

    int i = blockIdx.x * 256 + threadIdx.x;
    if (i >= NV) return;

    const int b = coors[4 * i + 0];
    const int z = coors[4 * i + 1];
    const int y = coors[4 * i + 2];
    const int x = coors[4 * i + 3];
    const float f0 = vf[3 * i + 0];
    const float f1 = vf[3 * i + 1];
    const float f2 = vf[3 * i + 2];

    int ozv[2], kzv[2], nz = 0;
    int oyv[2], kyv[2], ny = 0;
    int oxv[2], kxv[2], nx = 0;
#pragma unroll
    for (int k = 0; k < 3; ++k) {
        int t = z + 1 - k;
        if (t >= 0 && !(t & 1)) { int o = t >> 1; if (o < 21) { ozv[nz] = o; kzv[nz] = k; ++nz; } }
    }
#pragma unroll
    for (int k = 0; k < 3; ++k) {
        int t = y + 1 - k;
        if (t >= 0 && !(t & 1)) { int o = t >> 1; if (o < 256) { oyv[ny] = o; kyv[ny] = k; ++ny; } }
    }
#pragma unroll
    for (int k = 0; k < 3; ++k) {
        int t = x + 1 - k;
        if (t >= 0 && !(t & 1)) { int o = t >> 1; if (o < 256) { oxv[nx] = o; kxv[nx] = k; ++nx; } }
    }

    for (int a = 0; a < nz; ++a)
        for (int bb = 0; bb < ny; ++bb)
            for (int c = 0; c < nx; ++c) {
                const int oz = ozv[a], oy = oyv[bb], ox = oxv[c];
                const int tap = (kzv[a] * 3 + kyv[bb]) * 3 + kxv[c];
                const int sp = ((b * 21 + oz) * 256 + oy) * 256 + ox;
                m1[sp] = 1.0f;
                const int base = (b * 16) * 1376256 + oz * 65536 + oy * 256 + ox;
#pragma unroll
                for (int oc = 0; oc < 16; ++oc) {
                    const float s = ws[oc * 81 + tap] * f0 + ws[oc * 81 + 27 + tap] * f1 +
                                    ws[oc * 81 + 54 + tap] * f2;
                    atomicAdd(&y1[base + oc * 1376256], s);
                }
            }
}

// ---------------- Layer 2: dense conv 16->32, k3, s2, pad(1,1,1) ----------------
// 32x8 spatial tile; 16 oc per block (oc-group from blockIdx -> uniform weights).
__global__ __launch_bounds__(256) __attribute__((amdgpu_waves_per_eu(2, 4)))
void conv_l2(
    const float* __restrict__ y1, const float* __restrict__ m1,
    const float* __restrict__ wT2, const float* __restrict__ shb,
    const float* __restrict__ g1, const float* __restrict__ bb1,
    const float* __restrict__ rm1, const float* __restrict__ rv1,
    float* __restrict__ h2, float* __restrict__ m2)
{
    __shared__ float sIn[3 * 17 * 65];
    __shared__ float sM[3 * 17 * 65];
    const int tid = threadIdx.x;
    const int tx = tid & 31, ty = tid >> 5;             // 32 x 8 spatial tile
    const int ocg = blockIdx.x >> 2;                    // 0..1 (16 oc each)
    const int ox0 = (blockIdx.x & 3) * 32, oy0 = blockIdx.y * 8;
    const int bz = blockIdx.z;
    const int b = bz / 11, oz = bz % 11;
    const int iz0 = 2 * oz - 1, iy0 = 2 * oy0 - 1, ix0 = 2 * ox0 - 1;

    for (int e = tid; e < 3 * 17 * 65; e += 256) {
        const int ez = e / 1105, r = e % 1105, ey = r / 65, ex = r % 65;
        const int iz = iz0 + ez, iy = iy0 + ey, ix = ix0 + ex;
        float mv = 0.f;
        if ((unsigned)iz < 21u && (unsigned)iy < 256u && (unsigned)ix < 256u)
            mv = m1[((b * 21 + iz) * 256 + iy) * 256 + ix];
        sM[e] = mv;
    }
    __syncthreads();

    float msum = 0.f;
#pragma unroll
    for (int kz = 0; kz < 3; ++kz)
#pragma unroll
        for (int ky = 0; ky < 3; ++ky)
#pragma unroll
            for (int kx = 0; kx < 3; ++kx)
                msum += sM[(kz * 17 + 2 * ty + ky) * 65 + 2 * tx + kx];
    const float mout = msum > 0.f ? 1.f : 0.f;

    float acc[16];
#pragma unroll
    for (int oc = 0; oc < 16; ++oc) acc[oc] = 0.f;

#pragma unroll 1
    for (int cin = 0; cin < 16; ++cin) {
        const float inv = g1[cin] * rsqrtf(rv1[cin] + EPS);
        const float sh = bb1[cin] - rm1[cin] * inv;
        for (int e = tid; e < 3 * 17 * 65; e += 256) {
            const int ez = e / 1105, r = e % 1105, ey = r / 65, ex = r % 65;
            const int iz = iz0 + ez, iy = iy0 + ey, ix = ix0 + ex;
            float v = 0.f;
            if ((unsigned)iz < 21u && (unsigned)iy < 256u && (unsigned)ix < 256u) {
                const float yv = y1[(((b * 16 + cin) * 21 + iz) * 256 + iy) * 256 + ix];
                v = fmaxf(yv * inv + sh, 0.f) * sM[e];
            }
            sIn[e] = v;
        }
        __syncthreads();

        const float* __restrict__ wq = wT2 + cin * 27 * 32 + ocg * 16;  // block-uniform
#pragma unroll
        for (int kz = 0; kz < 3; ++kz)
#pragma unroll
            for (int ky = 0; ky < 3; ++ky)
#pragma unroll
                for (int kx = 0; kx < 3; ++kx) {
                    const int tap = (kz * 3 + ky) * 3 + kx;
                    const float vt = sIn[(kz * 17 + 2 * ty + ky) * 65 + 2 * tx + kx];
#pragma unroll
                    for (int oc = 0; oc < 16; ++oc)
                        acc[oc] = fmaf(wq[tap * 32 + oc], vt, acc[oc]);
                }
        __syncthreads();
    }

    const int oy = oy0 + ty, ox = ox0 + tx;
    if (ocg == 0) m2[((b * 11 + oz) * 128 + oy) * 128 + ox] = mout;
#pragma unroll
    for (int oc = 0; oc < 16; ++oc) {
        const int ocgl = ocg * 16 + oc;
        h2[(((b * 32 + ocgl) * 11 + oz) * 128 + oy) * 128 + ox] =
            fmaxf(acc[oc] + shb[ocgl], 0.f) * mout;
    }
}

// ---------------- Layer 3: dense conv 32->64, k3, s2, pad(0,1,1) ----------------
// 16x16 spatial tile; 16 oc per block (4 oc-groups from blockIdx).
__global__ __launch_bounds__(256) __attribute__((amdgpu_waves_per_eu(2, 4)))
void conv_l3(
    const float* __restrict__ h2, const float* __restrict__ m2,
    const float* __restrict__ wT3, const float* __restrict__ shb,
    float* __restrict__ h3, float* __restrict__ m3)
{
    __shared__ float sIn[3 * 33 * 33];
    __shared__ float sM[3 * 33 * 33];
    const int tid = threadIdx.x;
    const int tx = tid & 15, ty = tid >> 4;             // 16 x 16 spatial tile
    const int ocg = blockIdx.x >> 2;                    // 0..3 (16 oc each)
    const int ox0 = (blockIdx.x & 3) * 16, oy0 = blockIdx.y * 16;
    const int bz = blockIdx.z;
    const int b = bz / 5, oz = bz % 5;
    const int iz0 = 2 * oz, iy0 = 2 * oy0 - 1, ix0 = 2 * ox0 - 1;  // z pad 0

    for (int e = tid; e < 3 * 33 * 33; e += 256) {
        const int ez = e / 1089, rr = e % 1089, ey = rr / 33, ex = rr % 33;
        const int iz = iz0 + ez, iy = iy0 + ey, ix = ix0 + ex;
        float mv = 0.f;
        if ((unsigned)iy < 128u && (unsigned)ix < 128u)  // iz always in [0,10]
            mv = m2[((b * 11 + iz) * 128 + iy) * 128 + ix];
        sM[e] = mv;
    }
    __syncthreads();

    float msum = 0.f;
#pragma unroll
    for (int kz = 0; kz < 3; ++kz)
#pragma unroll
        for (int ky = 0; ky < 3; ++ky)
#pragma unroll
            for (int kx = 0; kx < 3; ++kx)
                msum += sM[kz * 1089 + (2 * ty + ky) * 33 + 2 * tx + kx];
    const float mout = msum > 0.f ? 1.f : 0.f;

    float acc[16];
#pragma unroll
    for (int oc = 0; oc < 16; ++oc) acc[oc] = 0.f;

#pragma unroll 1
    for (int cin = 0; cin < 32; ++cin) {
        for (int e = tid; e < 3 * 33 * 33; e += 256) {
            const int ez = e / 1089, rr = e % 1089, ey = rr / 33, ex = rr % 33;
            const int iz = iz0 + ez, iy = iy0 + ey, ix = ix0 + ex;
            float v = 0.f;
            if ((unsigned)iy < 128u && (unsigned)ix < 128u)
                v = h2[(((b * 32 + cin) * 11 + iz) * 128 + iy) * 128 + ix];
            sIn[e] = v;
        }
        __syncthreads();

        const float* __restrict__ wq = wT3 + cin * 27 * 64 + ocg * 16;  // block-uniform
#pragma unroll
        for (int kz = 0; kz < 3; ++kz)
#pragma unroll
            for (int ky = 0; ky < 3; ++ky)
#pragma unroll
                for (int kx = 0; kx < 3; ++kx) {
                    const int tap = (kz * 3 + ky) * 3 + kx;
                    const float vt = sIn[kz * 1089 + (2 * ty + ky) * 33 + 2 * tx + kx];
#pragma unroll
                    for (int oc = 0; oc < 16; ++oc)
                        acc[oc] = fmaf(wq[tap * 64 + oc], vt, acc[oc]);
                }
        __syncthreads();
    }

    const int oy = oy0 + ty, ox = ox0 + tx;
    if (ocg == 0) m3[(b * 5 + oz) * 4096 + oy * 64 + ox] = mout;
#pragma unroll
    for (int oc = 0; oc < 16; ++oc) {
        const int ocgl = ocg * 16 + oc;
        h3[(((b * 64 + ocgl) * 5 + oz) * 64 + oy) * 64 + ox] =
            fmaxf(acc[oc] + shb[32 + ocgl], 0.f) * mout;
    }
}

// ---------------- Layer 4: conv 64->64, k(3,1,1), s(2,1,1), pad 0 ----------------
// 16 oc per block (4 oc-groups), weights block-uniform.
__global__ __launch_bounds__(256) __attribute__((amdgpu_waves_per_eu(2, 4)))
void conv_l4(
    const float* __restrict__ h3, const float* __restrict__ m3,
    const float* __restrict__ wT4, const float* __restrict__ shb,
    float* __restrict__ out)
{
    const int p = blockIdx.x * 256 + threadIdx.x;  // 0..4095 spatial
    const int bo = blockIdx.y;
    const int b = bo >> 3, od = (bo >> 2) & 1, ocg = bo & 3;

    const float msum = m3[(b * 5 + 2 * od + 0) * 4096 + p] +
                       m3[(b * 5 + 2 * od + 1) * 4096 + p] +
                       m3[(b * 5 + 2 * od + 2) * 4096 + p];
    const float mout = msum > 0.f ? 1.f : 0.f;

    float acc[16];
#pragma unroll
    for (int oc = 0; oc < 16; ++oc) acc[oc] = 0.f;

#pragma unroll 1
    for (int c = 0; c < 64; ++c) {
        const float v0 = h3[((b * 64 + c) * 5 + 2 * od + 0) * 4096 + p];
        const float v1 = h3[((b * 64 + c) * 5 + 2 * od + 1) * 4096 + p];
        const float v2 = h3[((b * 64 + c) * 5 + 2 * od + 2) * 4096 + p];
        const float* __restrict__ wq = wT4 + c * 192 + ocg * 16;  // block-uniform
#pragma unroll
        for (int oc = 0; oc < 16; ++oc) {
            acc[oc] = fmaf(wq[oc], v0,
                      fmaf(wq[64 + oc], v1,
                      fmaf(wq[128 + oc], v2, acc[oc])));
        }
    }

#pragma unroll
    for (int oc = 0; oc < 16; ++oc) {
        const int ocgl = ocg * 16 + oc;
        out[((b * 64 + ocgl) * 2 + od) * 4096 + p] =
            fmaxf(acc[oc] + shb[96 + ocgl], 0.f) * mout;
    }
}

extern "C" void kernel_launch(void* const* d_in, const int* in_sizes, int n_in,
                              void* d_out, int out_size, void* d_ws, size_t ws_size,
                              hipStream_t stream)
{
    const float* vf    = (const float*)d_in[0];
    const int*   coors = (const int*)d_in[1];
    // d_in[2] = batch_size (==2, hardcoded in geometry)
    const float* w1 = (const float*)d_in[3];
    const float* g1 = (const float*)d_in[4];
    const float* b1 = (const float*)d_in[5];
    const float* rm1 = (const float*)d_in[6];
    const float* rv1 = (const float*)d_in[7];
    const float* w2 = (const float*)d_in[8];
    const float* g2 = (const float*)d_in[9];
    const float* b2 = (const float*)d_in[10];
    const float* rm2 = (const float*)d_in[11];
    const float* rv2 = (const float*)d_in[12];
    const float* w3 = (const float*)d_in[13];
    const float* g3 = (const float*)d_in[14];
    const float* b3 = (const float*)d_in[15];
    const float* rm3 = (const float*)d_in[16];
    const float* rv3 = (const float*)d_in[17];
    const float* w4 = (const float*)d_in[18];
    const float* g4 = (const float*)d_in[19];
    const float* b4 = (const float*)d_in[20];
    const float* rm4 = (const float*)d_in[21];
    const float* rv4 = (const float*)d_in[22];

    const int NV = in_sizes[0] / 3;

    float* ws = (float*)d_ws;
    float* y1  = ws;                   // 44,040,192 f  (2,16,21,256,256)
    float* m1  = y1 + 44040192;        //  2,752,512 f  (2,21,256,256)
    float* h2  = m1 + 2752512;         // 11,534,336 f  (2,32,11,128,128)
    float* m2  = h2 + 11534336;        //    360,448 f  (2,11,128,128)
    float* h3  = m2 + 360448;          //  2,621,440 f  (2,64,5,64,64)
    float* m3  = h3 + 2621440;         //     40,960 f  (2,5,64,64)
    float* wT2 = m3 + 40960;           //     13,824 f
    float* wT3 = wT2 + 13824;          //     55,296 f
    float* wT4 = wT3 + 55296;          //     12,288 f
    float* shb = wT4 + 12288;          //        160 f

    // zero the scatter accumulator + mask (y1 and m1 are contiguous)
    hipMemsetAsync(y1, 0, (size_t)(44040192 + 2752512) * sizeof(float), stream);

    repack<<<319, 256, 0, stream>>>(w2, g2, b2, rm2, rv2, w3, g3, b3, rm3, rv3,
                                    w4, g4, b4, rm4, rv4, wT2, wT3, wT4, shb);
    scatter_l1<<<(NV + 255) / 256, 256, 0, stream>>>(vf, coors, NV, w1, y1, m1);
    conv_l2<<<dim3(8, 16, 22), 256, 0, stream>>>(y1, m1, wT2, shb,
                                                 g1, b1, rm1, rv1, h2, m2);
    conv_l3<<<dim3(16, 4, 10), 256, 0, stream>>>(h2, m2, wT3, shb, h3, m3);
    conv_l4<<<dim3(16, 16), 256, 0, stream>>>(h3, m3, wT4, shb, (float*)d_out);
}

// Round 4
// 985.357 us; speedup vs baseline: 2.7028x; 1.0077x over previous
//
#include <hip/hip_runtime.h>

#define EPS 1e-3f

// Tensor geometry (fixed for this problem):
// L1 out (y1): (2,16,21,256,256)  m1: (2,21,256,256)
// L2 out (h2): (2,32,11,128,128)  m2: (2,11,128,128)
// L3 out (h3): (2,64,5,64,64)     m3: (2,5,64,64)
// L4 out:      (2,64,2,64,64) -> d_out (2,128,64,64) same layout
//
// Lessons encoded here:
//  - Weight pointers must be BLOCK-uniform (scalar s_load path); thread-dependent
//    weight indexing caused a 3.6x regression in round 2.
//  - Big per-thread arrays (acc[32]) are fine IF the rest of the live set is small;
//    amdgpu_waves_per_eu(4,8) lifts the VGPR cap to 128 so the compiler won't spill.
//  - Staging address/bounds math hoisted out of the cin loop into 13 precomputed
//    register offsets + mask values (branchless predication via mask multiply).

// ---------------- Weight repack + BN fold ----------------
__global__ __launch_bounds__(256) void repack(
    const float* __restrict__ w2, const float* __restrict__ g2, const float* __restrict__ b2,
    const float* __restrict__ rm2, const float* __restrict__ rv2,
    const float* __restrict__ w3, const float* __restrict__ g3, const float* __restrict__ b3,
    const float* __restrict__ rm3, const float* __restrict__ rv3,
    const float* __restrict__ w4, const float* __restrict__ g4, const float* __restrict__ b4,
    const float* __restrict__ rm4, const float* __restrict__ rv4,
    float* __restrict__ wT2, float* __restrict__ wT3, float* __restrict__ wT4,
    float* __restrict__ shb)
{
    const int i = blockIdx.x * 256 + threadIdx.x;
    if (i < 13824) {                       // wT2[(cin*27+tap)*32+oc], 16x27x32
        const int cin = i / 864, tap = (i / 32) % 27, oc = i & 31;
        const float inv = g2[oc] * rsqrtf(rv2[oc] + EPS);
        wT2[i] = w2[(oc * 16 + cin) * 27 + tap] * inv;
    } else if (i < 69120) {                // wT3[(cin*27+tap)*64+oc], 32x27x64
        const int j = i - 13824;
        const int cin = j / 1728, tap = (j / 64) % 27, oc = j & 63;
        const float inv = g3[oc] * rsqrtf(rv3[oc] + EPS);
        wT3[j] = w3[(oc * 32 + cin) * 27 + tap] * inv;
    } else if (i < 81408) {                // wT4[(c*3+kz)*64+oc], 64x3x64
        const int j = i - 69120;
        const int c = j / 192, kz = (j / 64) % 3, oc = j & 63;
        const float inv = g4[oc] * rsqrtf(rv4[oc] + EPS);
        wT4[j] = w4[(oc * 64 + c) * 3 + kz] * inv;
    } else if (i < 81568) {                // shifts: sh2[32], sh3[64], sh4[64]
        const int j = i - 81408;
        if (j < 32) {
            const float inv = g2[j] * rsqrtf(rv2[j] + EPS);
            shb[j] = b2[j] - rm2[j] * inv;
        } else if (j < 96) {
            const int o = j - 32;
            const float inv = g3[o] * rsqrtf(rv3[o] + EPS);
            shb[j] = b3[o] - rm3[o] * inv;
        } else {
            const int o = j - 96;
            const float inv = g4[o] * rsqrtf(rv4[o] + EPS);
            shb[j] = b4[o] - rm4[o] * inv;
        }
    }
}

// ---------------- Layer 1: voxel scatter, one thread per (voxel, oc) ----------------
// 16x the parallelism of thread-per-voxel: each thread issues <=8 independent
// atomics instead of 128 dependent ones (round-3 profile: scatter was
// latency-serialized at 0.5% VALUBusy).
__global__ __launch_bounds__(256) void scatter_l1(
    const float* __restrict__ vf, const int* __restrict__ coors, int NV,
    const float* __restrict__ w1, float* __restrict__ y1, float* __restrict__ m1)
{
    __shared__ float ws[16 * 3 * 27];  // (oc, c, tap)
    for (int e = threadIdx.x; e < 16 * 3 * 27; e += 256) ws[e] = w1[e];
    __syncthreads();

    const int gid = blockIdx.x * 256 + threadIdx.x;
    const int i = gid >> 4;        // voxel
    const int oc = gid & 15;       // channel
    if (i >= NV) return;

    const int b = coors[4 * i + 0];
    const int z = coors[4 * i + 1];
    const int y = coors[4 * i + 2];
    const int x = coors[4 * i + 3];
    const float f0 = vf[3 * i + 0];
    const float f1 = vf[3 * i + 1];
    const float f2 = vf[3 * i + 2];

    int ozv[2], kzv[2], nz = 0;
    int oyv[2], kyv[2], ny = 0;
    int oxv[2], kxv[2], nx = 0;
#pragma unroll
    for (int k = 0; k < 3; ++k) {
        int t = z + 1 - k;
        if (t >= 0 && !(t & 1)) { int o = t >> 1; if (o < 21) { ozv[nz] = o; kzv[nz] = k; ++nz; } }
    }
#pragma unroll
    for (int k = 0; k < 3; ++k) {
        int t = y + 1 - k;
        if (t >= 0 && !(t & 1)) { int o = t >> 1; if (o < 256) { oyv[ny] = o; kyv[ny] = k; ++ny; } }
    }
#pragma unroll
    for (int k = 0; k < 3; ++k) {
        int t = x + 1 - k;
        if (t >= 0 && !(t & 1)) { int o = t >> 1; if (o < 256) { oxv[nx] = o; kxv[nx] = k; ++nx; } }
    }

    for (int a = 0; a < nz; ++a)
        for (int bb = 0; bb < ny; ++bb)
            for (int c = 0; c < nx; ++c) {
                const int oz = ozv[a], oy = oyv[bb], ox = oxv[c];
                const int tap = (kzv[a] * 3 + kyv[bb]) * 3 + kxv[c];
                const int sp = ((b * 21 + oz) * 256 + oy) * 256 + ox;
                if (oc == 0) m1[sp] = 1.0f;
                const float s = ws[oc * 81 + tap] * f0 + ws[oc * 81 + 27 + tap] * f1 +
                                ws[oc * 81 + 54 + tap] * f2;
                atomicAdd(&y1[(b * 16 + oc) * 1376256 + oz * 65536 + oy * 256 + ox], s);
            }
}

// ---------------- Layer 2: dense conv 16->32, k3, s2, pad(1,1,1) ----------------
// 32x8 spatial tile, all 32 oc per block. Staging offsets precomputed.
#define NE2 3315            // 3*17*65
#define PAD2 3328           // 13*256
__global__ __launch_bounds__(256) __attribute__((amdgpu_waves_per_eu(4, 8)))
void conv_l2(
    const float* __restrict__ y1, const float* __restrict__ m1,
    const float* __restrict__ wT2, const float* __restrict__ shb,
    const float* __restrict__ g1, const float* __restrict__ bb1,
    const float* __restrict__ rm1, const float* __restrict__ rv1,
    float* __restrict__ h2, float* __restrict__ m2)
{
    __shared__ float sIn[PAD2];
    __shared__ float sM[PAD2];
    const int tid = threadIdx.x;
    const int tx = tid & 31, ty = tid >> 5;             // 32 x 8 spatial tile
    const int ox0 = blockIdx.x * 32, oy0 = blockIdx.y * 8;
    const int bz = blockIdx.z;
    const int b = bz / 11, oz = bz % 11;
    const int iz0 = 2 * oz - 1, iy0 = 2 * oy0 - 1, ix0 = 2 * ox0 - 1;

    for (int e = tid; e < NE2; e += 256) {
        const int ez = e / 1105, r = e % 1105, ey = r / 65, ex = r % 65;
        const int iz = iz0 + ez, iy = iy0 + ey, ix = ix0 + ex;
        float mv = 0.f;
        if ((unsigned)iz < 21u && (unsigned)iy < 256u && (unsigned)ix < 256u)
            mv = m1[((b * 21 + iz) * 256 + iy) * 256 + ix];
        sM[e] = mv;
    }
    __syncthreads();

    float msum = 0.f;
#pragma unroll
    for (int kz = 0; kz < 3; ++kz)
#pragma unroll
        for (int ky = 0; ky < 3; ++ky)
#pragma unroll
            for (int kx = 0; kx < 3; ++kx)
                msum += sM[(kz * 17 + 2 * ty + ky) * 65 + 2 * tx + kx];
    const float mout = msum > 0.f ? 1.f : 0.f;

    // Precompute per-thread staging offsets (plane-relative) + mask values.
    int   q13[13];
    float mk13[13];
#pragma unroll
    for (int j = 0; j < 13; ++j) {
        const int e = tid + j * 256;
        const int ez = e / 1105, r = e % 1105, ey = r / 65, ex = r % 65;
        const int iz = iz0 + ez, iy = iy0 + ey, ix = ix0 + ex;
        const bool ok = (e < NE2) && (unsigned)iz < 21u && (unsigned)iy < 256u &&
                        (unsigned)ix < 256u;
        q13[j] = ok ? (b * 16 * 1376256 + iz * 65536 + iy * 256 + ix) : 0;
        mk13[j] = ok ? sM[e] : 0.f;
    }

    float acc[32];
#pragma unroll
    for (int oc = 0; oc < 32; ++oc) acc[oc] = 0.f;

#pragma unroll 1
    for (int cin = 0; cin < 16; ++cin) {
        const float inv = g1[cin] * rsqrtf(rv1[cin] + EPS);
        const float sh = bb1[cin] - rm1[cin] * inv;
        const int coff = cin * 1376256;
#pragma unroll
        for (int j = 0; j < 13; ++j) {
            const float yv = y1[q13[j] + coff];
            sIn[tid + j * 256] = fmaxf(yv * inv + sh, 0.f) * mk13[j];
        }
        __syncthreads();

        const float* __restrict__ wq = wT2 + cin * 864;   // block-uniform
#pragma unroll
        for (int kz = 0; kz < 3; ++kz)
#pragma unroll
            for (int ky = 0; ky < 3; ++ky)
#pragma unroll
                for (int kx = 0; kx < 3; ++kx) {
                    const int tap = (kz * 3 + ky) * 3 + kx;
                    const float vt = sIn[(kz * 17 + 2 * ty + ky) * 65 + 2 * tx + kx];
#pragma unroll
                    for (int oc = 0; oc < 32; ++oc)
                        acc[oc] = fmaf(wq[tap * 32 + oc], vt, acc[oc]);
                }
        __syncthreads();
    }

    const int oy = oy0 + ty, ox = ox0 + tx;
    m2[((b * 11 + oz) * 128 + oy) * 128 + ox] = mout;
#pragma unroll
    for (int oc = 0; oc < 32; ++oc) {
        h2[(((b * 32 + oc) * 11 + oz) * 128 + oy) * 128 + ox] =
            fmaxf(acc[oc] + shb[oc], 0.f) * mout;
    }
}

// ---------------- Layer 3: dense conv 32->64, k3, s2, pad(0,1,1) ----------------
// 16x16 spatial tile; 32 oc per block (2 oc-groups from blockIdx).
#define NE3 3267            // 3*33*33
#define PAD3 3328
__global__ __launch_bounds__(256) __attribute__((amdgpu_waves_per_eu(4, 8)))
void conv_l3(
    const float* __restrict__ h2, const float* __restrict__ m2,
    const float* __restrict__ wT3, const float* __restrict__ shb,
    float* __restrict__ h3, float* __restrict__ m3)
{
    __shared__ float sIn[PAD3];
    __shared__ float sM[PAD3];
    const int tid = threadIdx.x;
    const int tx = tid & 15, ty = tid >> 4;             // 16 x 16 spatial tile
    const int ocg = blockIdx.x >> 2;                    // 0..1 (32 oc each)
    const int ox0 = (blockIdx.x & 3) * 16, oy0 = blockIdx.y * 16;
    const int bz = blockIdx.z;
    const int b = bz / 5, oz = bz % 5;
    const int iz0 = 2 * oz, iy0 = 2 * oy0 - 1, ix0 = 2 * ox0 - 1;  // z pad 0

    for (int e = tid; e < NE3; e += 256) {
        const int ez = e / 1089, rr = e % 1089, ey = rr / 33, ex = rr % 33;
        const int iz = iz0 + ez, iy = iy0 + ey, ix = ix0 + ex;
        float mv = 0.f;
        if ((unsigned)iy < 128u && (unsigned)ix < 128u)  // iz always in [0,10]
            mv = m2[((b * 11 + iz) * 128 + iy) * 128 + ix];
        sM[e] = mv;
    }
    __syncthreads();

    float msum = 0.f;
#pragma unroll
    for (int kz = 0; kz < 3; ++kz)
#pragma unroll
        for (int ky = 0; ky < 3; ++ky)
#pragma unroll
            for (int kx = 0; kx < 3; ++kx)
                msum += sM[kz * 1089 + (2 * ty + ky) * 33 + 2 * tx + kx];
    const float mout = msum > 0.f ? 1.f : 0.f;

    int   q13[13];
    float mk13[13];
#pragma unroll
    for (int j = 0; j < 13; ++j) {
        const int e = tid + j * 256;
        const int ez = e / 1089, rr = e % 1089, ey = rr / 33, ex = rr % 33;
        const int iz = iz0 + ez, iy = iy0 + ey, ix = ix0 + ex;
        const bool ok = (e < NE3) && (unsigned)iy < 128u && (unsigned)ix < 128u;
        q13[j] = ok ? (b * 5767168 + iz * 16384 + iy * 128 + ix) : 0;
        mk13[j] = ok ? sM[e] : 0.f;
    }

    float acc[32];
#pragma unroll
    for (int oc = 0; oc < 32; ++oc) acc[oc] = 0.f;

#pragma unroll 1
    for (int cin = 0; cin < 32; ++cin) {
        const int coff = cin * 180224;
#pragma unroll
        for (int j = 0; j < 13; ++j) {
            sIn[tid + j * 256] = h2[q13[j] + coff] * (mk13[j] != 0.f ? 1.f : 1.f);
        }
        __syncthreads();

        const float* __restrict__ wq = wT3 + cin * 1728 + ocg * 32;  // block-uniform
#pragma unroll
        for (int kz = 0; kz < 3; ++kz)
#pragma unroll
            for (int ky = 0; ky < 3; ++ky)
#pragma unroll
                for (int kx = 0; kx < 3; ++kx) {
                    const int tap = (kz * 3 + ky) * 3 + kx;
                    const float vt = sIn[kz * 1089 + (2 * ty + ky) * 33 + 2 * tx + kx];
#pragma unroll
                    for (int oc = 0; oc < 32; ++oc)
                        acc[oc] = fmaf(wq[tap * 64 + oc], vt, acc[oc]);
                }
        __syncthreads();
    }

    const int oy = oy0 + ty, ox = ox0 + tx;
    if (ocg == 0) m3[(b * 5 + oz) * 4096 + oy * 64 + ox] = mout;
#pragma unroll
    for (int oc = 0; oc < 32; ++oc) {
        const int ocgl = ocg * 32 + oc;
        h3[(((b * 64 + ocgl) * 5 + oz) * 64 + oy) * 64 + ox] =
            fmaxf(acc[oc] + shb[32 + ocgl], 0.f) * mout;
    }
}

// ---------------- Layer 4: conv 64->64, k(3,1,1), s(2,1,1), pad 0 ----------------
// 32 oc per block (2 oc-groups), weights block-uniform.
__global__ __launch_bounds__(256) __attribute__((amdgpu_waves_per_eu(4, 8)))
void conv_l4(
    const float* __restrict__ h3, const float* __restrict__ m3,
    const float* __restrict__ wT4, const float* __restrict__ shb,
    float* __restrict__ out)
{
    const int p = blockIdx.x * 256 + threadIdx.x;  // 0..4095 spatial
    const int bo = blockIdx.y;
    const int b = bo >> 2, od = (bo >> 1) & 1, ocg = bo & 1;

    const float msum = m3[(b * 5 + 2 * od + 0) * 4096 + p] +
                       m3[(b * 5 + 2 * od + 1) * 4096 + p] +
                       m3[(b * 5 + 2 * od + 2) * 4096 + p];
    const float mout = msum > 0.f ? 1.f : 0.f;

    float acc[32];
#pragma unroll
    for (int oc = 0; oc < 32; ++oc) acc[oc] = 0.f;

#pragma unroll 1
    for (int c = 0; c < 64; ++c) {
        const float v0 = h3[((b * 64 + c) * 5 + 2 * od + 0) * 4096 + p];
        const float v1 = h3[((b * 64 + c) * 5 + 2 * od + 1) * 4096 + p];
        const float v2 = h3[((b * 64 + c) * 5 + 2 * od + 2) * 4096 + p];
        const float* __restrict__ wq = wT4 + c * 192 + ocg * 32;  // block-uniform
#pragma unroll
        for (int oc = 0; oc < 32; ++oc) {
            acc[oc] = fmaf(wq[oc], v0,
                      fmaf(wq[64 + oc], v1,
                      fmaf(wq[128 + oc], v2, acc[oc])));
        }
    }

#pragma unroll
    for (int oc = 0; oc < 32; ++oc) {
        const int ocgl = ocg * 32 + oc;
        out[((b * 64 + ocgl) * 2 + od) * 4096 + p] =
            fmaxf(acc[oc] + shb[96 + ocgl], 0.f) * mout;
    }
}

extern "C" void kernel_launch(void* const* d_in, const int* in_sizes, int n_in,
                              void* d_out, int out_size, void* d_ws, size_t ws_size,
                              hipStream_t stream)
{
    const float* vf    = (const float*)d_in[0];
    const int*   coors = (const int*)d_in[1];
    // d_in[2] = batch_size (==2, hardcoded in geometry)
    const float* w1 = (const float*)d_in[3];
    const float* g1 = (const float*)d_in[4];
    const float* b1 = (const float*)d_in[5];
    const float* rm1 = (const float*)d_in[6];
    const float* rv1 = (const float*)d_in[7];
    const float* w2 = (const float*)d_in[8];
    const float* g2 = (const float*)d_in[9];
    const float* b2 = (const float*)d_in[10];
    const float* rm2 = (const float*)d_in[11];
    const float* rv2 = (const float*)d_in[12];
    const float* w3 = (const float*)d_in[13];
    const float* g3 = (const float*)d_in[14];
    const float* b3 = (const float*)d_in[15];
    const float* rm3 = (const float*)d_in[16];
    const float* rv3 = (const float*)d_in[17];
    const float* w4 = (const float*)d_in[18];
    const float* g4 = (const float*)d_in[19];
    const float* b4 = (const float*)d_in[20];
    const float* rm4 = (const float*)d_in[21];
    const float* rv4 = (const float*)d_in[22];

    const int NV = in_sizes[0] / 3;

    float* ws = (float*)d_ws;
    float* y1  = ws;                   // 44,040,192 f  (2,16,21,256,256)
    float* m1  = y1 + 44040192;        //  2,752,512 f  (2,21,256,256)
    float* h2  = m1 + 2752512;         // 11,534,336 f  (2,32,11,128,128)
    float* m2  = h2 + 11534336;        //    360,448 f  (2,11,128,128)
    float* h3  = m2 + 360448;          //  2,621,440 f  (2,64,5,64,64)
    float* m3  = h3 + 2621440;         //     40,960 f  (2,5,64,64)
    float* wT2 = m3 + 40960;           //     13,824 f
    float* wT3 = wT2 + 13824;          //     55,296 f
    float* wT4 = wT3 + 55296;          //     12,288 f
    float* shb = wT4 + 12288;          //        160 f

    // zero the scatter accumulator + mask (y1 and m1 are contiguous)
    hipMemsetAsync(y1, 0, (size_t)(44040192 + 2752512) * sizeof(float), stream);

    repack<<<319, 256, 0, stream>>>(w2, g2, b2, rm2, rv2, w3, g3, b3, rm3, rv3,
                                    w4, g4, b4, rm4, rv4, wT2, wT3, wT4, shb);
    scatter_l1<<<(NV * 16 + 255) / 256, 256, 0, stream>>>(vf, coors, NV, w1, y1, m1);
    conv_l2<<<dim3(4, 16, 22), 256, 0, stream>>>(y1, m1, wT2, shb,
                                                 g1, b1, rm1, rv1, h2, m2);
    conv_l3<<<dim3(8, 4, 10), 256, 0, stream>>>(h2, m2, wT3, shb, h3, m3);
    conv_l4<<<dim3(16, 8), 256, 0, stream>>>(h3, m3, wT4, shb, (float*)d_out);
}

// Round 5
// 723.594 us; speedup vs baseline: 3.6806x; 1.3618x over previous
//
#include <hip/hip_runtime.h>

#define EPS 1e-3f

// Tensor geometry (fixed for this problem):
// L1 out (y1): (2,16,21,256,256)  m1: (2,21,256,256)
// L2 out (h2): (2,32,11,128,128)  m2: (2,11,128,128)
// L3 out (h3): (2,64,5,64,64)     m3: (2,5,64,64)
// L4 out:      (2,64,2,64,64) -> d_out (2,128,64,64) same layout
//
// Lessons encoded:
//  - Weight pointers must be BLOCK-uniform (scalar s_load path). (round 2: 3.6x regression)
//  - amdgpu_waves_per_eu(4,8) keeps the allocator from spilling acc arrays. (round 1/3)
//  - Staging addr/bounds math hoisted out of the cin loop. (round 4)
//  - Occupancy is grid-limited for the deep layers: conv_l3 @320 blocks ran at
//    14.6% occupancy, VALUBusy 22% (round 4). Fix: 128-thr blocks, 4 oc-groups,
//    cin-split x2 into fp32 partials (overlaid on dead y1) + combine kernel.

// ---------------- Weight repack + BN fold ----------------
__global__ __launch_bounds__(256) void repack(
    const float* __restrict__ w2, const float* __restrict__ g2, const float* __restrict__ b2,
    const float* __restrict__ rm2, const float* __restrict__ rv2,
    const float* __restrict__ w3, const float* __restrict__ g3, const float* __restrict__ b3,
    const float* __restrict__ rm3, const float* __restrict__ rv3,
    const float* __restrict__ w4, const float* __restrict__ g4, const float* __restrict__ b4,
    const float* __restrict__ rm4, const float* __restrict__ rv4,
    float* __restrict__ wT2, float* __restrict__ wT3, float* __restrict__ wT4,
    float* __restrict__ shb)
{
    const int i = blockIdx.x * 256 + threadIdx.x;
    if (i < 13824) {                       // wT2[(cin*27+tap)*32+oc], 16x27x32
        const int cin = i / 864, tap = (i / 32) % 27, oc = i & 31;
        const float inv = g2[oc] * rsqrtf(rv2[oc] + EPS);
        wT2[i] = w2[(oc * 16 + cin) * 27 + tap] * inv;
    } else if (i < 69120) {                // wT3[(cin*27+tap)*64+oc], 32x27x64
        const int j = i - 13824;
        const int cin = j / 1728, tap = (j / 64) % 27, oc = j & 63;
        const float inv = g3[oc] * rsqrtf(rv3[oc] + EPS);
        wT3[j] = w3[(oc * 32 + cin) * 27 + tap] * inv;
    } else if (i < 81408) {                // wT4[(c*3+kz)*64+oc], 64x3x64
        const int j = i - 69120;
        const int c = j / 192, kz = (j / 64) % 3, oc = j & 63;
        const float inv = g4[oc] * rsqrtf(rv4[oc] + EPS);
        wT4[j] = w4[(oc * 64 + c) * 3 + kz] * inv;
    } else if (i < 81568) {                // shifts: sh2[32], sh3[64], sh4[64]
        const int j = i - 81408;
        if (j < 32) {
            const float inv = g2[j] * rsqrtf(rv2[j] + EPS);
            shb[j] = b2[j] - rm2[j] * inv;
        } else if (j < 96) {
            const int o = j - 32;
            const float inv = g3[o] * rsqrtf(rv3[o] + EPS);
            shb[j] = b3[o] - rm3[o] * inv;
        } else {
            const int o = j - 96;
            const float inv = g4[o] * rsqrtf(rv4[o] + EPS);
            shb[j] = b4[o] - rm4[o] * inv;
        }
    }
}

// ---------------- Layer 1: voxel scatter, one thread per (voxel, oc) ----------------
__global__ __launch_bounds__(256) void scatter_l1(
    const float* __restrict__ vf, const int* __restrict__ coors, int NV,
    const float* __restrict__ w1, float* __restrict__ y1, float* __restrict__ m1)
{
    __shared__ float ws[16 * 3 * 27];  // (oc, c, tap)
    for (int e = threadIdx.x; e < 16 * 3 * 27; e += 256) ws[e] = w1[e];
    __syncthreads();

    const int gid = blockIdx.x * 256 + threadIdx.x;
    const int i = gid >> 4;        // voxel
    const int oc = gid & 15;       // channel
    if (i >= NV) return;

    const int b = coors[4 * i + 0];
    const int z = coors[4 * i + 1];
    const int y = coors[4 * i + 2];
    const int x = coors[4 * i + 3];
    const float f0 = vf[3 * i + 0];
    const float f1 = vf[3 * i + 1];
    const float f2 = vf[3 * i + 2];

    int ozv[2], kzv[2], nz = 0;
    int oyv[2], kyv[2], ny = 0;
    int oxv[2], kxv[2], nx = 0;
#pragma unroll
    for (int k = 0; k < 3; ++k) {
        int t = z + 1 - k;
        if (t >= 0 && !(t & 1)) { int o = t >> 1; if (o < 21) { ozv[nz] = o; kzv[nz] = k; ++nz; } }
    }
#pragma unroll
    for (int k = 0; k < 3; ++k) {
        int t = y + 1 - k;
        if (t >= 0 && !(t & 1)) { int o = t >> 1; if (o < 256) { oyv[ny] = o; kyv[ny] = k; ++ny; } }
    }
#pragma unroll
    for (int k = 0; k < 3; ++k) {
        int t = x + 1 - k;
        if (t >= 0 && !(t & 1)) { int o = t >> 1; if (o < 256) { oxv[nx] = o; kxv[nx] = k; ++nx; } }
    }

    for (int a = 0; a < nz; ++a)
        for (int bb = 0; bb < ny; ++bb)
            for (int c = 0; c < nx; ++c) {
                const int oz = ozv[a], oy = oyv[bb], ox = oxv[c];
                const int tap = (kzv[a] * 3 + kyv[bb]) * 3 + kxv[c];
                const int sp = ((b * 21 + oz) * 256 + oy) * 256 + ox;
                if (oc == 0) m1[sp] = 1.0f;
                const float s = ws[oc * 81 + tap] * f0 + ws[oc * 81 + 27 + tap] * f1 +
                                ws[oc * 81 + 54 + tap] * f2;
                atomicAdd(&y1[(b * 16 + oc) * 1376256 + oz * 65536 + oy * 256 + ox], s);
            }
}

// ---------------- Layer 2: dense conv 16->32, k3, s2, pad(1,1,1) ----------------
// 32x8 spatial tile, all 32 oc per block. Staging offsets precomputed.
#define NE2 3315            // 3*17*65
#define PAD2 3328           // 13*256
__global__ __launch_bounds__(256) __attribute__((amdgpu_waves_per_eu(4, 8)))
void conv_l2(
    const float* __restrict__ y1, const float* __restrict__ m1,
    const float* __restrict__ wT2, const float* __restrict__ shb,
    const float* __restrict__ g1, const float* __restrict__ bb1,
    const float* __restrict__ rm1, const float* __restrict__ rv1,
    float* __restrict__ h2, float* __restrict__ m2)
{
    __shared__ float sIn[PAD2];
    __shared__ float sM[PAD2];
    const int tid = threadIdx.x;
    const int tx = tid & 31, ty = tid >> 5;             // 32 x 8 spatial tile
    const int ox0 = blockIdx.x * 32, oy0 = blockIdx.y * 8;
    const int bz = blockIdx.z;
    const int b = bz / 11, oz = bz % 11;
    const int iz0 = 2 * oz - 1, iy0 = 2 * oy0 - 1, ix0 = 2 * ox0 - 1;

    for (int e = tid; e < NE2; e += 256) {
        const int ez = e / 1105, r = e % 1105, ey = r / 65, ex = r % 65;
        const int iz = iz0 + ez, iy = iy0 + ey, ix = ix0 + ex;
        float mv = 0.f;
        if ((unsigned)iz < 21u && (unsigned)iy < 256u && (unsigned)ix < 256u)
            mv = m1[((b * 21 + iz) * 256 + iy) * 256 + ix];
        sM[e] = mv;
    }
    __syncthreads();

    float msum = 0.f;
#pragma unroll
    for (int kz = 0; kz < 3; ++kz)
#pragma unroll
        for (int ky = 0; ky < 3; ++ky)
#pragma unroll
            for (int kx = 0; kx < 3; ++kx)
                msum += sM[(kz * 17 + 2 * ty + ky) * 65 + 2 * tx + kx];
    const float mout = msum > 0.f ? 1.f : 0.f;

    // Precompute per-thread staging offsets + mask values (hoisted).
    int   q13[13];
    float mk13[13];
#pragma unroll
    for (int j = 0; j < 13; ++j) {
        const int e = tid + j * 256;
        const int ez = e / 1105, r = e % 1105, ey = r / 65, ex = r % 65;
        const int iz = iz0 + ez, iy = iy0 + ey, ix = ix0 + ex;
        const bool ok = (e < NE2) && (unsigned)iz < 21u && (unsigned)iy < 256u &&
                        (unsigned)ix < 256u;
        q13[j] = ok ? (b * 16 * 1376256 + iz * 65536 + iy * 256 + ix) : 0;
        mk13[j] = ok ? sM[e] : 0.f;
    }

    float acc[32];
#pragma unroll
    for (int oc = 0; oc < 32; ++oc) acc[oc] = 0.f;

#pragma unroll 1
    for (int cin = 0; cin < 16; ++cin) {
        const float inv = g1[cin] * rsqrtf(rv1[cin] + EPS);
        const float sh = bb1[cin] - rm1[cin] * inv;
        const int coff = cin * 1376256;
#pragma unroll
        for (int j = 0; j < 13; ++j) {
            const float yv = y1[q13[j] + coff];
            sIn[tid + j * 256] = fmaxf(yv * inv + sh, 0.f) * mk13[j];
        }
        __syncthreads();

        const float* __restrict__ wq = wT2 + cin * 864;   // block-uniform
#pragma unroll
        for (int kz = 0; kz < 3; ++kz)
#pragma unroll
            for (int ky = 0; ky < 3; ++ky)
#pragma unroll
                for (int kx = 0; kx < 3; ++kx) {
                    const int tap = (kz * 3 + ky) * 3 + kx;
                    const float vt = sIn[(kz * 17 + 2 * ty + ky) * 65 + 2 * tx + kx];
#pragma unroll
                    for (int oc = 0; oc < 32; ++oc)
                        acc[oc] = fmaf(wq[tap * 32 + oc], vt, acc[oc]);
                }
        __syncthreads();
    }

    const int oy = oy0 + ty, ox = ox0 + tx;
    m2[((b * 11 + oz) * 128 + oy) * 128 + ox] = mout;
#pragma unroll
    for (int oc = 0; oc < 32; ++oc) {
        h2[(((b * 32 + oc) * 11 + oz) * 128 + oy) * 128 + ox] =
            fmaxf(acc[oc] + shb[oc], 0.f) * mout;
    }
}

// ---------------- Layer 3 (partial): conv 32->64, k3, s2, pad(0,1,1) ----------------
// 128-thr blocks, 16x8 px tile, 16 oc/thread (4 oc-groups), cin split in 2.
// Writes raw partial sums; activation+mask in combine_l3. Grid (16, 8, 20).
#define NE3 1683            // 3*17*33
#define PAD3 1792           // 14*128
__global__ __launch_bounds__(128) __attribute__((amdgpu_waves_per_eu(4, 8)))
void conv_l3(
    const float* __restrict__ h2, const float* __restrict__ m2,
    const float* __restrict__ wT3,
    float* __restrict__ p3a, float* __restrict__ p3b, float* __restrict__ m3)
{
    __shared__ float sIn[PAD3];
    __shared__ float sM[PAD3];
    const int tid = threadIdx.x;
    const int tx = tid & 15, ty = tid >> 4;             // 16 x 8 spatial tile
    const int ocg = blockIdx.x >> 2;                    // 0..3 (16 oc each)
    const int ox0 = (blockIdx.x & 3) * 16, oy0 = blockIdx.y * 8;
    const int bz = blockIdx.z;
    const int half = bz / 10, rz = bz % 10;
    const int b = rz / 5, oz = rz % 5;
    const int iz0 = 2 * oz, iy0 = 2 * oy0 - 1, ix0 = 2 * ox0 - 1;  // z pad 0

    const bool needM = (half == 0) && (ocg == 0);
    if (needM) {
        for (int e = tid; e < NE3; e += 128) {
            const int ez = e / 561, rr = e % 561, ey = rr / 33, ex = rr % 33;
            const int iz = iz0 + ez, iy = iy0 + ey, ix = ix0 + ex;
            float mv = 0.f;
            if ((unsigned)iy < 128u && (unsigned)ix < 128u)  // iz always in [0,10]
                mv = m2[((b * 11 + iz) * 128 + iy) * 128 + ix];
            sM[e] = mv;
        }
        __syncthreads();
    }

    // Hoisted staging offsets + in-bounds 0/1 multipliers (fixes r4 OOB-garbage bug).
    int   q14[14];
    float ok14[14];
#pragma unroll
    for (int j = 0; j < 14; ++j) {
        const int e = tid + j * 128;
        const int ez = e / 561, rr = e % 561, ey = rr / 33, ex = rr % 33;
        const int iz = iz0 + ez, iy = iy0 + ey, ix = ix0 + ex;
        const bool ok = (e < NE3) && (unsigned)iy < 128u && (unsigned)ix < 128u;
        q14[j] = ok ? (b * 5767168 + iz * 16384 + iy * 128 + ix) : 0;
        ok14[j] = ok ? 1.f : 0.f;
    }

    float acc[16];
#pragma unroll
    for (int oc = 0; oc < 16; ++oc) acc[oc] = 0.f;

#pragma unroll 1
    for (int c = 0; c < 16; ++c) {
        const int cin = half * 16 + c;
        const int coff = cin * 180224;
#pragma unroll
        for (int j = 0; j < 14; ++j)
            sIn[tid + j * 128] = h2[q14[j] + coff] * ok14[j];
        __syncthreads();

        const float* __restrict__ wq = wT3 + cin * 1728 + ocg * 16;  // block-uniform
#pragma unroll
        for (int kz = 0; kz < 3; ++kz)
#pragma unroll
            for (int ky = 0; ky < 3; ++ky)
#pragma unroll
                for (int kx = 0; kx < 3; ++kx) {
                    const int tap = (kz * 3 + ky) * 3 + kx;
                    const float vt = sIn[kz * 561 + (2 * ty + ky) * 33 + 2 * tx + kx];
#pragma unroll
                    for (int oc = 0; oc < 16; ++oc)
                        acc[oc] = fmaf(wq[tap * 64 + oc], vt, acc[oc]);
                }
        __syncthreads();
    }

    const int oy = oy0 + ty, ox = ox0 + tx;
    if (needM) {
        float msum = 0.f;
#pragma unroll
        for (int kz = 0; kz < 3; ++kz)
#pragma unroll
            for (int ky = 0; ky < 3; ++ky)
#pragma unroll
                for (int kx = 0; kx < 3; ++kx)
                    msum += sM[kz * 561 + (2 * ty + ky) * 33 + 2 * tx + kx];
        m3[(b * 5 + oz) * 4096 + oy * 64 + ox] = msum > 0.f ? 1.f : 0.f;
    }

    float* __restrict__ part = half ? p3b : p3a;
#pragma unroll
    for (int oc = 0; oc < 16; ++oc) {
        const int ocgl = ocg * 16 + oc;
        part[(((b * 64 + ocgl) * 5 + oz) * 64 + oy) * 64 + ox] = acc[oc];
    }
}

// ---------------- Layer 3 combine: h3 = relu(pa+pb+shift)*m3 ----------------
__global__ __launch_bounds__(256) void combine_l3(
    const float* __restrict__ p3a, const float* __restrict__ p3b,
    const float* __restrict__ m3, const float* __restrict__ shb,
    float* __restrict__ h3)
{
    const int idx = blockIdx.x * 256 + threadIdx.x;   // < 2,621,440
    const int b = idx / 1310720;
    const int r = idx - b * 1310720;
    const int oc = r / 20480;
    const int r2 = r - oc * 20480;
    const float mv = m3[b * 20480 + r2];
    h3[idx] = fmaxf(p3a[idx] + p3b[idx] + shb[32 + oc], 0.f) * mv;
}

// ---------------- Layer 4: conv 64->64, k(3,1,1), s(2,1,1), pad 0 ----------------
// 8 oc per block (8 oc-groups) for grid parallelism (512 blocks).
__global__ __launch_bounds__(256) __attribute__((amdgpu_waves_per_eu(4, 8)))
void conv_l4(
    const float* __restrict__ h3, const float* __restrict__ m3,
    const float* __restrict__ wT4, const float* __restrict__ shb,
    float* __restrict__ out)
{
    const int p = blockIdx.x * 256 + threadIdx.x;  // 0..4095 spatial
    const int bo = blockIdx.y;
    const int b = bo >> 4, od = (bo >> 3) & 1, ocg = bo & 7;

    const float msum = m3[(b * 5 + 2 * od + 0) * 4096 + p] +
                       m3[(b * 5 + 2 * od + 1) * 4096 + p] +
                       m3[(b * 5 + 2 * od + 2) * 4096 + p];
    const float mout = msum > 0.f ? 1.f : 0.f;

    float acc[8];
#pragma unroll
    for (int oc = 0; oc < 8; ++oc) acc[oc] = 0.f;

#pragma unroll 1
    for (int c = 0; c < 64; ++c) {
        const float v0 = h3[((b * 64 + c) * 5 + 2 * od + 0) * 4096 + p];
        const float v1 = h3[((b * 64 + c) * 5 + 2 * od + 1) * 4096 + p];
        const float v2 = h3[((b * 64 + c) * 5 + 2 * od + 2) * 4096 + p];
        const float* __restrict__ wq = wT4 + c * 192 + ocg * 8;  // block-uniform
#pragma unroll
        for (int oc = 0; oc < 8; ++oc) {
            acc[oc] = fmaf(wq[oc], v0,
                      fmaf(wq[64 + oc], v1,
                      fmaf(wq[128 + oc], v2, acc[oc])));
        }
    }

#pragma unroll
    for (int oc = 0; oc < 8; ++oc) {
        const int ocgl = ocg * 8 + oc;
        out[((b * 64 + ocgl) * 2 + od) * 4096 + p] =
            fmaxf(acc[oc] + shb[96 + ocgl], 0.f) * mout;
    }
}

extern "C" void kernel_launch(void* const* d_in, const int* in_sizes, int n_in,
                              void* d_out, int out_size, void* d_ws, size_t ws_size,
                              hipStream_t stream)
{
    const float* vf    = (const float*)d_in[0];
    const int*   coors = (const int*)d_in[1];
    // d_in[2] = batch_size (==2, hardcoded in geometry)
    const float* w1 = (const float*)d_in[3];
    const float* g1 = (const float*)d_in[4];
    const float* b1 = (const float*)d_in[5];
    const float* rm1 = (const float*)d_in[6];
    const float* rv1 = (const float*)d_in[7];
    const float* w2 = (const float*)d_in[8];
    const float* g2 = (const float*)d_in[9];
    const float* b2 = (const float*)d_in[10];
    const float* rm2 = (const float*)d_in[11];
    const float* rv2 = (const float*)d_in[12];
    const float* w3 = (const float*)d_in[13];
    const float* g3 = (const float*)d_in[14];
    const float* b3 = (const float*)d_in[15];
    const float* rm3 = (const float*)d_in[16];
    const float* rv3 = (const float*)d_in[17];
    const float* w4 = (const float*)d_in[18];
    const float* g4 = (const float*)d_in[19];
    const float* b4 = (const float*)d_in[20];
    const float* rm4 = (const float*)d_in[21];
    const float* rv4 = (const float*)d_in[22];

    const int NV = in_sizes[0] / 3;

    float* ws = (float*)d_ws;
    float* y1  = ws;                   // 44,040,192 f  (2,16,21,256,256)
    float* m1  = y1 + 44040192;        //  2,752,512 f  (2,21,256,256)
    float* h2  = m1 + 2752512;         // 11,534,336 f  (2,32,11,128,128)
    float* m2  = h2 + 11534336;        //    360,448 f  (2,11,128,128)
    float* h3  = m2 + 360448;          //  2,621,440 f  (2,64,5,64,64)
    float* m3  = h3 + 2621440;         //     40,960 f  (2,5,64,64)
    float* wT2 = m3 + 40960;           //     13,824 f
    float* wT3 = wT2 + 13824;          //     55,296 f
    float* wT4 = wT3 + 55296;          //     12,288 f
    float* shb = wT4 + 12288;          //        160 f
    // Partial buffers for conv_l3 overlay the y1 region (y1 dead after conv_l2).
    float* p3a = y1;                   //  2,621,440 f
    float* p3b = y1 + 2621440;         //  2,621,440 f

    // zero the scatter accumulator + mask (y1 and m1 are contiguous)
    hipMemsetAsync(y1, 0, (size_t)(44040192 + 2752512) * sizeof(float), stream);

    repack<<<319, 256, 0, stream>>>(w2, g2, b2, rm2, rv2, w3, g3, b3, rm3, rv3,
                                    w4, g4, b4, rm4, rv4, wT2, wT3, wT4, shb);
    scatter_l1<<<(NV * 16 + 255) / 256, 256, 0, stream>>>(vf, coors, NV, w1, y1, m1);
    conv_l2<<<dim3(4, 16, 22), 256, 0, stream>>>(y1, m1, wT2, shb,
                                                 g1, b1, rm1, rv1, h2, m2);
    conv_l3<<<dim3(16, 8, 20), 128, 0, stream>>>(h2, m2, wT3, p3a, p3b, m3);
    combine_l3<<<10240, 256, 0, stream>>>(p3a, p3b, m3, shb, h3);
    conv_l4<<<dim3(16, 32), 256, 0, stream>>>(h3, m3, wT4, shb, (float*)d_out);
}

// Round 6
// 656.799 us; speedup vs baseline: 4.0549x; 1.1017x over previous
//
#include <hip/hip_runtime.h>

#define EPS 1e-3f

// Tensor geometry (fixed for this problem):
// y1 (L1 pre-act): interleaved (2, 4, 21,256,256, 4)  = (b, c/4, z,y,x, c%4)
// m1: (2,21,256,256)
// L2 out (h2): (2,32,11,128,128)  m2: (2,11,128,128)
// L3 out (h3): (2,64,5,64,64)     m3: (2,5,64,64)
// L4 out:      (2,64,2,64,64) -> d_out (2,128,64,64) same layout
//
// Lessons encoded:
//  - Weight pointers must be BLOCK-uniform (scalar s_load path). (r2: 3.6x regression)
//  - amdgpu_waves_per_eu(4,8) keeps the allocator from spilling acc arrays. (r1/r3)
//  - Occupancy is grid-limited for deep layers -> conv_l3 cin-split + combine. (r4/r5)
//  - Scatter was memory-REQUEST bound: channel-major y1 put consecutive lanes
//    5.5 MB apart (64 lines per wave-atomic). Channel-quad interleave makes
//    lanes 0-3 write 16 contiguous bytes -> 16 lines per wave-atomic. (r5)

// ---------------- Weight repack + BN fold ----------------
__global__ __launch_bounds__(256) void repack(
    const float* __restrict__ w2, const float* __restrict__ g2, const float* __restrict__ b2,
    const float* __restrict__ rm2, const float* __restrict__ rv2,
    const float* __restrict__ w3, const float* __restrict__ g3, const float* __restrict__ b3,
    const float* __restrict__ rm3, const float* __restrict__ rv3,
    const float* __restrict__ w4, const float* __restrict__ g4, const float* __restrict__ b4,
    const float* __restrict__ rm4, const float* __restrict__ rv4,
    float* __restrict__ wT2, float* __restrict__ wT3, float* __restrict__ wT4,
    float* __restrict__ shb)
{
    const int i = blockIdx.x * 256 + threadIdx.x;
    if (i < 13824) {                       // wT2[(cin*27+tap)*32+oc], 16x27x32
        const int cin = i / 864, tap = (i / 32) % 27, oc = i & 31;
        const float inv = g2[oc] * rsqrtf(rv2[oc] + EPS);
        wT2[i] = w2[(oc * 16 + cin) * 27 + tap] * inv;
    } else if (i < 69120) {                // wT3[(cin*27+tap)*64+oc], 32x27x64
        const int j = i - 13824;
        const int cin = j / 1728, tap = (j / 64) % 27, oc = j & 63;
        const float inv = g3[oc] * rsqrtf(rv3[oc] + EPS);
        wT3[j] = w3[(oc * 32 + cin) * 27 + tap] * inv;
    } else if (i < 81408) {                // wT4[(c*3+kz)*64+oc], 64x3x64
        const int j = i - 69120;
        const int c = j / 192, kz = (j / 64) % 3, oc = j & 63;
        const float inv = g4[oc] * rsqrtf(rv4[oc] + EPS);
        wT4[j] = w4[(oc * 64 + c) * 3 + kz] * inv;
    } else if (i < 81568) {                // shifts: sh2[32], sh3[64], sh4[64]
        const int j = i - 81408;
        if (j < 32) {
            const float inv = g2[j] * rsqrtf(rv2[j] + EPS);
            shb[j] = b2[j] - rm2[j] * inv;
        } else if (j < 96) {
            const int o = j - 32;
            const float inv = g3[o] * rsqrtf(rv3[o] + EPS);
            shb[j] = b3[o] - rm3[o] * inv;
        } else {
            const int o = j - 96;
            const float inv = g4[o] * rsqrtf(rv4[o] + EPS);
            shb[j] = b4[o] - rm4[o] * inv;
        }
    }
}

// ---------------- Layer 1: voxel scatter, one thread per (voxel, oc) ----------------
// y1 layout (b, oc/4, z,y,x, oc%4): lanes 0-3 of a voxel hit one 16B span.
__global__ __launch_bounds__(256) void scatter_l1(
    const float* __restrict__ vf, const int* __restrict__ coors, int NV,
    const float* __restrict__ w1, float* __restrict__ y1, float* __restrict__ m1)
{
    __shared__ float ws[16 * 3 * 27];  // (oc, c, tap)
    for (int e = threadIdx.x; e < 16 * 3 * 27; e += 256) ws[e] = w1[e];
    __syncthreads();

    const int gid = blockIdx.x * 256 + threadIdx.x;
    const int i = gid >> 4;        // voxel
    const int oc = gid & 15;       // channel
    if (i >= NV) return;
    const int oc4 = oc >> 2, ocl = oc & 3;

    const int b = coors[4 * i + 0];
    const int z = coors[4 * i + 1];
    const int y = coors[4 * i + 2];
    const int x = coors[4 * i + 3];
    const float f0 = vf[3 * i + 0];
    const float f1 = vf[3 * i + 1];
    const float f2 = vf[3 * i + 2];

    int ozv[2], kzv[2], nz = 0;
    int oyv[2], kyv[2], ny = 0;
    int oxv[2], kxv[2], nx = 0;
#pragma unroll
    for (int k = 0; k < 3; ++k) {
        int t = z + 1 - k;
        if (t >= 0 && !(t & 1)) { int o = t >> 1; if (o < 21) { ozv[nz] = o; kzv[nz] = k; ++nz; } }
    }
#pragma unroll
    for (int k = 0; k < 3; ++k) {
        int t = y + 1 - k;
        if (t >= 0 && !(t & 1)) { int o = t >> 1; if (o < 256) { oyv[ny] = o; kyv[ny] = k; ++ny; } }
    }
#pragma unroll
    for (int k = 0; k < 3; ++k) {
        int t = x + 1 - k;
        if (t >= 0 && !(t & 1)) { int o = t >> 1; if (o < 256) { oxv[nx] = o; kxv[nx] = k; ++nx; } }
    }

    for (int a = 0; a < nz; ++a)
        for (int bb = 0; bb < ny; ++bb)
            for (int c = 0; c < nx; ++c) {
                const int oz = ozv[a], oy = oyv[bb], ox = oxv[c];
                const int tap = (kzv[a] * 3 + kyv[bb]) * 3 + kxv[c];
                const int sp = oz * 65536 + oy * 256 + ox;
                if (oc == 0) m1[b * 1376256 + sp] = 1.0f;
                const float s = ws[oc * 81 + tap] * f0 + ws[oc * 81 + 27 + tap] * f1 +
                                ws[oc * 81 + 54 + tap] * f2;
                atomicAdd(&y1[(b * 4 + oc4) * 5505024 + sp * 4 + ocl], s);
            }
}

// ---------------- Layer 2: dense conv 16->32, k3, s2, pad(1,1,1) ----------------
// 32x8 spatial tile, all 32 oc per block. cin in 4 groups of 4: coalesced
// float4 loads from the interleaved y1, transposed into 4 LDS planes.
#define NE2 3315            // 3*17*65
#define PAD2 3328           // 13*256
__global__ __launch_bounds__(256) __attribute__((amdgpu_waves_per_eu(4, 8)))
void conv_l2(
    const float4* __restrict__ y14, const float* __restrict__ m1,
    const float* __restrict__ wT2, const float* __restrict__ shb,
    const float* __restrict__ g1, const float* __restrict__ bb1,
    const float* __restrict__ rm1, const float* __restrict__ rv1,
    float* __restrict__ h2, float* __restrict__ m2)
{
    __shared__ float sIn[4 * PAD2];      // mask staged here first, then 4 cin planes
    const int tid = threadIdx.x;
    const int tx = tid & 31, ty = tid >> 5;             // 32 x 8 spatial tile
    const int ox0 = blockIdx.x * 32, oy0 = blockIdx.y * 8;
    const int bz = blockIdx.z;
    const int b = bz / 11, oz = bz % 11;
    const int iz0 = 2 * oz - 1, iy0 = 2 * oy0 - 1, ix0 = 2 * ox0 - 1;

    // stage mask tile into sIn[0..NE2)
    for (int e = tid; e < NE2; e += 256) {
        const int ez = e / 1105, r = e % 1105, ey = r / 65, ex = r % 65;
        const int iz = iz0 + ez, iy = iy0 + ey, ix = ix0 + ex;
        float mv = 0.f;
        if ((unsigned)iz < 21u && (unsigned)iy < 256u && (unsigned)ix < 256u)
            mv = m1[b * 1376256 + iz * 65536 + iy * 256 + ix];
        sIn[e] = mv;
    }
    __syncthreads();

    float msum = 0.f;
#pragma unroll
    for (int kz = 0; kz < 3; ++kz)
#pragma unroll
        for (int ky = 0; ky < 3; ++ky)
#pragma unroll
            for (int kx = 0; kx < 3; ++kx)
                msum += sIn[(kz * 17 + 2 * ty + ky) * 65 + 2 * tx + kx];
    const float mout = msum > 0.f ? 1.f : 0.f;

    // hoisted per-thread staging offsets (float4-plane-relative) + mask values
    int   q13[13];
    float mk13[13];
#pragma unroll
    for (int j = 0; j < 13; ++j) {
        const int e = tid + j * 256;
        const int ez = e / 1105, r = e % 1105, ey = r / 65, ex = r % 65;
        const int iz = iz0 + ez, iy = iy0 + ey, ix = ix0 + ex;
        const bool ok = (e < NE2) && (unsigned)iz < 21u && (unsigned)iy < 256u &&
                        (unsigned)ix < 256u;
        q13[j] = ok ? (b * 4 * 1376256 + iz * 65536 + iy * 256 + ix) : 0;
        mk13[j] = ok ? sIn[e] : 0.f;
    }
    __syncthreads();   // mask consumed into registers; sIn now reusable

    float acc[32];
#pragma unroll
    for (int oc = 0; oc < 32; ++oc) acc[oc] = 0.f;

#pragma unroll 1
    for (int cg = 0; cg < 4; ++cg) {
        float inv[4], sh[4];
#pragma unroll
        for (int c = 0; c < 4; ++c) {
            const int cin = cg * 4 + c;
            inv[c] = g1[cin] * rsqrtf(rv1[cin] + EPS);
            sh[c] = bb1[cin] - rm1[cin] * inv[c];
        }
#pragma unroll
        for (int j = 0; j < 13; ++j) {
            const float4 v = y14[q13[j] + cg * 1376256];   // coalesced 16B/lane
            const int e = tid + j * 256;
            sIn[0 * PAD2 + e] = fmaxf(v.x * inv[0] + sh[0], 0.f) * mk13[j];
            sIn[1 * PAD2 + e] = fmaxf(v.y * inv[1] + sh[1], 0.f) * mk13[j];
            sIn[2 * PAD2 + e] = fmaxf(v.z * inv[2] + sh[2], 0.f) * mk13[j];
            sIn[3 * PAD2 + e] = fmaxf(v.w * inv[3] + sh[3], 0.f) * mk13[j];
        }
        __syncthreads();

#pragma unroll
        for (int c = 0; c < 4; ++c) {
            const float* __restrict__ wq = wT2 + (cg * 4 + c) * 864;   // block-uniform
#pragma unroll
            for (int kz = 0; kz < 3; ++kz)
#pragma unroll
                for (int ky = 0; ky < 3; ++ky)
#pragma unroll
                    for (int kx = 0; kx < 3; ++kx) {
                        const int tap = (kz * 3 + ky) * 3 + kx;
                        const float vt = sIn[c * PAD2 + (kz * 17 + 2 * ty + ky) * 65 +
                                             2 * tx + kx];
#pragma unroll
                        for (int oc = 0; oc < 32; ++oc)
                            acc[oc] = fmaf(wq[tap * 32 + oc], vt, acc[oc]);
                    }
        }
        __syncthreads();
    }

    const int oy = oy0 + ty, ox = ox0 + tx;
    m2[((b * 11 + oz) * 128 + oy) * 128 + ox] = mout;
#pragma unroll
    for (int oc = 0; oc < 32; ++oc) {
        h2[(((b * 32 + oc) * 11 + oz) * 128 + oy) * 128 + ox] =
            fmaxf(acc[oc] + shb[oc], 0.f) * mout;
    }
}

// ---------------- Layer 3 (partial): conv 32->64, k3, s2, pad(0,1,1) ----------------
// 128-thr blocks, 16x8 px tile, 16 oc/thread (4 oc-groups), cin split in 2.
#define NE3 1683            // 3*17*33
#define PAD3 1792           // 14*128
__global__ __launch_bounds__(128) __attribute__((amdgpu_waves_per_eu(4, 8)))
void conv_l3(
    const float* __restrict__ h2, const float* __restrict__ m2,
    const float* __restrict__ wT3,
    float* __restrict__ p3a, float* __restrict__ p3b, float* __restrict__ m3)
{
    __shared__ float sIn[PAD3];
    __shared__ float sM[PAD3];
    const int tid = threadIdx.x;
    const int tx = tid & 15, ty = tid >> 4;             // 16 x 8 spatial tile
    const int ocg = blockIdx.x >> 2;                    // 0..3 (16 oc each)
    const int ox0 = (blockIdx.x & 3) * 16, oy0 = blockIdx.y * 8;
    const int bz = blockIdx.z;
    const int half = bz / 10, rz = bz % 10;
    const int b = rz / 5, oz = rz % 5;
    const int iz0 = 2 * oz, iy0 = 2 * oy0 - 1, ix0 = 2 * ox0 - 1;  // z pad 0

    const bool needM = (half == 0) && (ocg == 0);
    if (needM) {
        for (int e = tid; e < NE3; e += 128) {
            const int ez = e / 561, rr = e % 561, ey = rr / 33, ex = rr % 33;
            const int iz = iz0 + ez, iy = iy0 + ey, ix = ix0 + ex;
            float mv = 0.f;
            if ((unsigned)iy < 128u && (unsigned)ix < 128u)  // iz always in [0,10]
                mv = m2[((b * 11 + iz) * 128 + iy) * 128 + ix];
            sM[e] = mv;
        }
        __syncthreads();
    }

    int   q14[14];
    float ok14[14];
#pragma unroll
    for (int j = 0; j < 14; ++j) {
        const int e = tid + j * 128;
        const int ez = e / 561, rr = e % 561, ey = rr / 33, ex = rr % 33;
        const int iz = iz0 + ez, iy = iy0 + ey, ix = ix0 + ex;
        const bool ok = (e < NE3) && (unsigned)iy < 128u && (unsigned)ix < 128u;
        q14[j] = ok ? (b * 5767168 + iz * 16384 + iy * 128 + ix) : 0;
        ok14[j] = ok ? 1.f : 0.f;
    }

    float acc[16];
#pragma unroll
    for (int oc = 0; oc < 16; ++oc) acc[oc] = 0.f;

#pragma unroll 1
    for (int c = 0; c < 16; ++c) {
        const int cin = half * 16 + c;
        const int coff = cin * 180224;
#pragma unroll
        for (int j = 0; j < 14; ++j)
            sIn[tid + j * 128] = h2[q14[j] + coff] * ok14[j];
        __syncthreads();

        const float* __restrict__ wq = wT3 + cin * 1728 + ocg * 16;  // block-uniform
#pragma unroll
        for (int kz = 0; kz < 3; ++kz)
#pragma unroll
            for (int ky = 0; ky < 3; ++ky)
#pragma unroll
                for (int kx = 0; kx < 3; ++kx) {
                    const int tap = (kz * 3 + ky) * 3 + kx;
                    const float vt = sIn[kz * 561 + (2 * ty + ky) * 33 + 2 * tx + kx];
#pragma unroll
                    for (int oc = 0; oc < 16; ++oc)
                        acc[oc] = fmaf(wq[tap * 64 + oc], vt, acc[oc]);
                }
        __syncthreads();
    }

    const int oy = oy0 + ty, ox = ox0 + tx;
    if (needM) {
        float msum = 0.f;
#pragma unroll
        for (int kz = 0; kz < 3; ++kz)
#pragma unroll
            for (int ky = 0; ky < 3; ++ky)
#pragma unroll
                for (int kx = 0; kx < 3; ++kx)
                    msum += sM[kz * 561 + (2 * ty + ky) * 33 + 2 * tx + kx];
        m3[(b * 5 + oz) * 4096 + oy * 64 + ox] = msum > 0.f ? 1.f : 0.f;
    }

    float* __restrict__ part = half ? p3b : p3a;
#pragma unroll
    for (int oc = 0; oc < 16; ++oc) {
        const int ocgl = ocg * 16 + oc;
        part[(((b * 64 + ocgl) * 5 + oz) * 64 + oy) * 64 + ox] = acc[oc];
    }
}

// ---------------- Layer 3 combine: h3 = relu(pa+pb+shift)*m3 ----------------
__global__ __launch_bounds__(256) void combine_l3(
    const float* __restrict__ p3a, const float* __restrict__ p3b,
    const float* __restrict__ m3, const float* __restrict__ shb,
    float* __restrict__ h3)
{
    const int idx = blockIdx.x * 256 + threadIdx.x;   // < 2,621,440
    const int b = idx / 1310720;
    const int r = idx - b * 1310720;
    const int oc = r / 20480;
    const int r2 = r - oc * 20480;
    const float mv = m3[b * 20480 + r2];
    h3[idx] = fmaxf(p3a[idx] + p3b[idx] + shb[32 + oc], 0.f) * mv;
}

// ---------------- Layer 4: conv 64->64, k(3,1,1), s(2,1,1), pad 0 ----------------
__global__ __launch_bounds__(256) __attribute__((amdgpu_waves_per_eu(4, 8)))
void conv_l4(
    const float* __restrict__ h3, const float* __restrict__ m3,
    const float* __restrict__ wT4, const float* __restrict__ shb,
    float* __restrict__ out)
{
    const int p = blockIdx.x * 256 + threadIdx.x;  // 0..4095 spatial
    const int bo = blockIdx.y;
    const int b = bo >> 4, od = (bo >> 3) & 1, ocg = bo & 7;

    const float msum = m3[(b * 5 + 2 * od + 0) * 4096 + p] +
                       m3[(b * 5 + 2 * od + 1) * 4096 + p] +
                       m3[(b * 5 + 2 * od + 2) * 4096 + p];
    const float mout = msum > 0.f ? 1.f : 0.f;

    float acc[8];
#pragma unroll
    for (int oc = 0; oc < 8; ++oc) acc[oc] = 0.f;

#pragma unroll 1
    for (int c = 0; c < 64; ++c) {
        const float v0 = h3[((b * 64 + c) * 5 + 2 * od + 0) * 4096 + p];
        const float v1 = h3[((b * 64 + c) * 5 + 2 * od + 1) * 4096 + p];
        const float v2 = h3[((b * 64 + c) * 5 + 2 * od + 2) * 4096 + p];
        const float* __restrict__ wq = wT4 + c * 192 + ocg * 8;  // block-uniform
#pragma unroll
        for (int oc = 0; oc < 8; ++oc) {
            acc[oc] = fmaf(wq[oc], v0,
                      fmaf(wq[64 + oc], v1,
                      fmaf(wq[128 + oc], v2, acc[oc])));
        }
    }

#pragma unroll
    for (int oc = 0; oc < 8; ++oc) {
        const int ocgl = ocg * 8 + oc;
        out[((b * 64 + ocgl) * 2 + od) * 4096 + p] =
            fmaxf(acc[oc] + shb[96 + ocgl], 0.f) * mout;
    }
}

extern "C" void kernel_launch(void* const* d_in, const int* in_sizes, int n_in,
                              void* d_out, int out_size, void* d_ws, size_t ws_size,
                              hipStream_t stream)
{
    const float* vf    = (const float*)d_in[0];
    const int*   coors = (const int*)d_in[1];
    // d_in[2] = batch_size (==2, hardcoded in geometry)
    const float* w1 = (const float*)d_in[3];
    const float* g1 = (const float*)d_in[4];
    const float* b1 = (const float*)d_in[5];
    const float* rm1 = (const float*)d_in[6];
    const float* rv1 = (const float*)d_in[7];
    const float* w2 = (const float*)d_in[8];
    const float* g2 = (const float*)d_in[9];
    const float* b2 = (const float*)d_in[10];
    const float* rm2 = (const float*)d_in[11];
    const float* rv2 = (const float*)d_in[12];
    const float* w3 = (const float*)d_in[13];
    const float* g3 = (const float*)d_in[14];
    const float* b3 = (const float*)d_in[15];
    const float* rm3 = (const float*)d_in[16];
    const float* rv3 = (const float*)d_in[17];
    const float* w4 = (const float*)d_in[18];
    const float* g4 = (const float*)d_in[19];
    const float* b4 = (const float*)d_in[20];
    const float* rm4 = (const float*)d_in[21];
    const float* rv4 = (const float*)d_in[22];

    const int NV = in_sizes[0] / 3;

    float* ws = (float*)d_ws;
    float* y1  = ws;                   // 44,040,192 f  (2,4,21,256,256,4) interleaved
    float* m1  = y1 + 44040192;        //  2,752,512 f  (2,21,256,256)
    float* h2  = m1 + 2752512;         // 11,534,336 f  (2,32,11,128,128)
    float* m2  = h2 + 11534336;        //    360,448 f  (2,11,128,128)
    float* h3  = m2 + 360448;          //  2,621,440 f  (2,64,5,64,64)
    float* m3  = h3 + 2621440;         //     40,960 f  (2,5,64,64)
    float* wT2 = m3 + 40960;           //     13,824 f
    float* wT3 = wT2 + 13824;          //     55,296 f
    float* wT4 = wT3 + 55296;          //     12,288 f
    float* shb = wT4 + 12288;          //        160 f
    // Partial buffers for conv_l3 overlay the y1 region (y1 dead after conv_l2).
    float* p3a = y1;                   //  2,621,440 f
    float* p3b = y1 + 2621440;         //  2,621,440 f

    // zero the scatter accumulator + mask (y1 and m1 are contiguous)
    hipMemsetAsync(y1, 0, (size_t)(44040192 + 2752512) * sizeof(float), stream);

    repack<<<319, 256, 0, stream>>>(w2, g2, b2, rm2, rv2, w3, g3, b3, rm3, rv3,
                                    w4, g4, b4, rm4, rv4, wT2, wT3, wT4, shb);
    scatter_l1<<<(NV * 16 + 255) / 256, 256, 0, stream>>>(vf, coors, NV, w1, y1, m1);
    conv_l2<<<dim3(4, 16, 22), 256, 0, stream>>>((const float4*)y1, m1, wT2, shb,
                                                 g1, b1, rm1, rv1, h2, m2);
    conv_l3<<<dim3(16, 8, 20), 128, 0, stream>>>(h2, m2, wT3, p3a, p3b, m3);
    combine_l3<<<10240, 256, 0, stream>>>(p3a, p3b, m3, shb, h3);
    conv_l4<<<dim3(16, 32), 256, 0, stream>>>(h3, m3, wT4, shb, (float*)d_out);
}

// Round 7
// 654.354 us; speedup vs baseline: 4.0700x; 1.0037x over previous
//
#include <hip/hip_runtime.h>

#define EPS 1e-3f

// Tensor geometry (fixed for this problem):
// y1 (L1 pre-act): interleaved (2, 4, 21,256,256, 4)  = (b, c/4, z,y,x, c%4)
// m1: (2,21,256,256)
// L2 out (h2): (2,32,11,128,128)  m2: (2,11,128,128)
// L3 out (h3): (2,64,5,64,64)     m3: (2,5,64,64)
// L4 out:      (2,64,2,64,64) -> d_out (2,128,64,64) same layout
//
// Lessons encoded:
//  - Weight pointers must be BLOCK-uniform (scalar s_load path). (r2: 3.6x regression)
//  - waves_per_eu attr keeps the allocator from spilling acc arrays. (r1/r3)
//  - Occupancy is grid-limited for deep layers -> conv_l3 cin-split + combine. (r4/r5)
//  - Scatter is memory-REQUEST bound -> channel-quad interleaved y1. (r5/r6)
//  - conv_l2 was 56% VALU-idle: per-phase global-load latency exposed behind the
//    barrier with only 3 resident blocks/CU. Fix: register prefetch of the next
//    cin-group's loads issued right after the publishing barrier. (r6)

// ---------------- Weight repack + BN fold ----------------
__global__ __launch_bounds__(256) void repack(
    const float* __restrict__ w2, const float* __restrict__ g2, const float* __restrict__ b2,
    const float* __restrict__ rm2, const float* __restrict__ rv2,
    const float* __restrict__ w3, const float* __restrict__ g3, const float* __restrict__ b3,
    const float* __restrict__ rm3, const float* __restrict__ rv3,
    const float* __restrict__ w4, const float* __restrict__ g4, const float* __restrict__ b4,
    const float* __restrict__ rm4, const float* __restrict__ rv4,
    float* __restrict__ wT2, float* __restrict__ wT3, float* __restrict__ wT4,
    float* __restrict__ shb)
{
    const int i = blockIdx.x * 256 + threadIdx.x;
    if (i < 13824) {                       // wT2[(cin*27+tap)*32+oc], 16x27x32
        const int cin = i / 864, tap = (i / 32) % 27, oc = i & 31;
        const float inv = g2[oc] * rsqrtf(rv2[oc] + EPS);
        wT2[i] = w2[(oc * 16 + cin) * 27 + tap] * inv;
    } else if (i < 69120) {                // wT3[(cin*27+tap)*64+oc], 32x27x64
        const int j = i - 13824;
        const int cin = j / 1728, tap = (j / 64) % 27, oc = j & 63;
        const float inv = g3[oc] * rsqrtf(rv3[oc] + EPS);
        wT3[j] = w3[(oc * 32 + cin) * 27 + tap] * inv;
    } else if (i < 81408) {                // wT4[(c*3+kz)*64+oc], 64x3x64
        const int j = i - 69120;
        const int c = j / 192, kz = (j / 64) % 3, oc = j & 63;
        const float inv = g4[oc] * rsqrtf(rv4[oc] + EPS);
        wT4[j] = w4[(oc * 64 + c) * 3 + kz] * inv;
    } else if (i < 81568) {                // shifts: sh2[32], sh3[64], sh4[64]
        const int j = i - 81408;
        if (j < 32) {
            const float inv = g2[j] * rsqrtf(rv2[j] + EPS);
            shb[j] = b2[j] - rm2[j] * inv;
        } else if (j < 96) {
            const int o = j - 32;
            const float inv = g3[o] * rsqrtf(rv3[o] + EPS);
            shb[j] = b3[o] - rm3[o] * inv;
        } else {
            const int o = j - 96;
            const float inv = g4[o] * rsqrtf(rv4[o] + EPS);
            shb[j] = b4[o] - rm4[o] * inv;
        }
    }
}

// ---------------- Layer 1: voxel scatter, one thread per (voxel, oc) ----------------
__global__ __launch_bounds__(256) void scatter_l1(
    const float* __restrict__ vf, const int* __restrict__ coors, int NV,
    const float* __restrict__ w1, float* __restrict__ y1, float* __restrict__ m1)
{
    __shared__ float ws[16 * 3 * 27];  // (oc, c, tap)
    for (int e = threadIdx.x; e < 16 * 3 * 27; e += 256) ws[e] = w1[e];
    __syncthreads();

    const int gid = blockIdx.x * 256 + threadIdx.x;
    const int i = gid >> 4;        // voxel
    const int oc = gid & 15;       // channel
    if (i >= NV) return;
    const int oc4 = oc >> 2, ocl = oc & 3;

    const int b = coors[4 * i + 0];
    const int z = coors[4 * i + 1];
    const int y = coors[4 * i + 2];
    const int x = coors[4 * i + 3];
    const float f0 = vf[3 * i + 0];
    const float f1 = vf[3 * i + 1];
    const float f2 = vf[3 * i + 2];

    int ozv[2], kzv[2], nz = 0;
    int oyv[2], kyv[2], ny = 0;
    int oxv[2], kxv[2], nx = 0;
#pragma unroll
    for (int k = 0; k < 3; ++k) {
        int t = z + 1 - k;
        if (t >= 0 && !(t & 1)) { int o = t >> 1; if (o < 21) { ozv[nz] = o; kzv[nz] = k; ++nz; } }
    }
#pragma unroll
    for (int k = 0; k < 3; ++k) {
        int t = y + 1 - k;
        if (t >= 0 && !(t & 1)) { int o = t >> 1; if (o < 256) { oyv[ny] = o; kyv[ny] = k; ++ny; } }
    }
#pragma unroll
    for (int k = 0; k < 3; ++k) {
        int t = x + 1 - k;
        if (t >= 0 && !(t & 1)) { int o = t >> 1; if (o < 256) { oxv[nx] = o; kxv[nx] = k; ++nx; } }
    }

    for (int a = 0; a < nz; ++a)
        for (int bb = 0; bb < ny; ++bb)
            for (int c = 0; c < nx; ++c) {
                const int oz = ozv[a], oy = oyv[bb], ox = oxv[c];
                const int tap = (kzv[a] * 3 + kyv[bb]) * 3 + kxv[c];
                const int sp = oz * 65536 + oy * 256 + ox;
                if (oc == 0) m1[b * 1376256 + sp] = 1.0f;
                const float s = ws[oc * 81 + tap] * f0 + ws[oc * 81 + 27 + tap] * f1 +
                                ws[oc * 81 + 54 + tap] * f2;
                atomicAdd(&y1[(b * 4 + oc4) * 5505024 + sp * 4 + ocl], s);
            }
}

// ---------------- Layer 2: dense conv 16->32, k3, s2, pad(1,1,1) ----------------
// 32x8 spatial tile, all 32 oc per block. cin in 4 groups of 4 (float4 loads,
// 4 LDS planes). Next group's loads register-prefetched under current compute.
#define NE2 3315            // 3*17*65
#define PAD2 3328           // 13*256
__global__ __launch_bounds__(256) __attribute__((amdgpu_waves_per_eu(3, 8)))
void conv_l2(
    const float4* __restrict__ y14, const float* __restrict__ m1,
    const float* __restrict__ wT2, const float* __restrict__ shb,
    const float* __restrict__ g1, const float* __restrict__ bb1,
    const float* __restrict__ rm1, const float* __restrict__ rv1,
    float* __restrict__ h2, float* __restrict__ m2)
{
    __shared__ float sIn[4 * PAD2];      // mask staged here first, then 4 cin planes
    const int tid = threadIdx.x;
    const int tx = tid & 31, ty = tid >> 5;             // 32 x 8 spatial tile
    const int ox0 = blockIdx.x * 32, oy0 = blockIdx.y * 8;
    const int bz = blockIdx.z;
    const int b = bz / 11, oz = bz % 11;
    const int iz0 = 2 * oz - 1, iy0 = 2 * oy0 - 1, ix0 = 2 * ox0 - 1;

    // stage mask tile into sIn[0..NE2)
    for (int e = tid; e < NE2; e += 256) {
        const int ez = e / 1105, r = e % 1105, ey = r / 65, ex = r % 65;
        const int iz = iz0 + ez, iy = iy0 + ey, ix = ix0 + ex;
        float mv = 0.f;
        if ((unsigned)iz < 21u && (unsigned)iy < 256u && (unsigned)ix < 256u)
            mv = m1[b * 1376256 + iz * 65536 + iy * 256 + ix];
        sIn[e] = mv;
    }
    __syncthreads();

    float msum = 0.f;
#pragma unroll
    for (int kz = 0; kz < 3; ++kz)
#pragma unroll
        for (int ky = 0; ky < 3; ++ky)
#pragma unroll
            for (int kx = 0; kx < 3; ++kx)
                msum += sIn[(kz * 17 + 2 * ty + ky) * 65 + 2 * tx + kx];
    const float mout = msum > 0.f ? 1.f : 0.f;

    // hoisted per-thread staging offsets (float4-plane-relative) + mask values
    int   q13[13];
    float mk13[13];
#pragma unroll
    for (int j = 0; j < 13; ++j) {
        const int e = tid + j * 256;
        const int ez = e / 1105, r = e % 1105, ey = r / 65, ex = r % 65;
        const int iz = iz0 + ez, iy = iy0 + ey, ix = ix0 + ex;
        const bool ok = (e < NE2) && (unsigned)iz < 21u && (unsigned)iy < 256u &&
                        (unsigned)ix < 256u;
        q13[j] = ok ? (b * 4 * 1376256 + iz * 65536 + iy * 256 + ix) : 0;
        mk13[j] = ok ? sIn[e] : 0.f;
    }

    // prefetch group 0
    float4 pre[13];
#pragma unroll
    for (int j = 0; j < 13; ++j) pre[j] = y14[q13[j]];

    __syncthreads();   // mask consumed into registers; sIn now reusable

    float acc[32];
#pragma unroll
    for (int oc = 0; oc < 32; ++oc) acc[oc] = 0.f;

#pragma unroll 1
    for (int cg = 0; cg < 4; ++cg) {
        float inv[4], sh[4];
#pragma unroll
        for (int c = 0; c < 4; ++c) {
            const int cin = cg * 4 + c;
            inv[c] = g1[cin] * rsqrtf(rv1[cin] + EPS);
            sh[c] = bb1[cin] - rm1[cin] * inv[c];
        }
#pragma unroll
        for (int j = 0; j < 13; ++j) {
            const float4 v = pre[j];
            const int e = tid + j * 256;
            sIn[0 * PAD2 + e] = fmaxf(v.x * inv[0] + sh[0], 0.f) * mk13[j];
            sIn[1 * PAD2 + e] = fmaxf(v.y * inv[1] + sh[1], 0.f) * mk13[j];
            sIn[2 * PAD2 + e] = fmaxf(v.z * inv[2] + sh[2], 0.f) * mk13[j];
            sIn[3 * PAD2 + e] = fmaxf(v.w * inv[3] + sh[3], 0.f) * mk13[j];
        }
        __syncthreads();        // LDS published

        // issue next group's loads NOW; latency hides under compute below
        if (cg < 3) {
#pragma unroll
            for (int j = 0; j < 13; ++j) pre[j] = y14[q13[j] + (cg + 1) * 1376256];
        }

#pragma unroll
        for (int c = 0; c < 4; ++c) {
            const float* __restrict__ wq = wT2 + (cg * 4 + c) * 864;   // block-uniform
#pragma unroll
            for (int kz = 0; kz < 3; ++kz)
#pragma unroll
                for (int ky = 0; ky < 3; ++ky)
#pragma unroll
                    for (int kx = 0; kx < 3; ++kx) {
                        const int tap = (kz * 3 + ky) * 3 + kx;
                        const float vt = sIn[c * PAD2 + (kz * 17 + 2 * ty + ky) * 65 +
                                             2 * tx + kx];
#pragma unroll
                        for (int oc = 0; oc < 32; ++oc)
                            acc[oc] = fmaf(wq[tap * 32 + oc], vt, acc[oc]);
                    }
        }
        __syncthreads();        // LDS consumed
    }

    const int oy = oy0 + ty, ox = ox0 + tx;
    m2[((b * 11 + oz) * 128 + oy) * 128 + ox] = mout;
#pragma unroll
    for (int oc = 0; oc < 32; ++oc) {
        h2[(((b * 32 + oc) * 11 + oz) * 128 + oy) * 128 + ox] =
            fmaxf(acc[oc] + shb[oc], 0.f) * mout;
    }
}

// ---------------- Layer 3 (partial): conv 32->64, k3, s2, pad(0,1,1) ----------------
// 128-thr blocks, 16x8 px tile, 16 oc/thread (4 oc-groups), cin split in 2.
// Next cin's loads register-prefetched under current compute.
#define NE3 1683            // 3*17*33
#define PAD3 1792           // 14*128
__global__ __launch_bounds__(128) __attribute__((amdgpu_waves_per_eu(4, 8)))
void conv_l3(
    const float* __restrict__ h2, const float* __restrict__ m2,
    const float* __restrict__ wT3,
    float* __restrict__ p3a, float* __restrict__ p3b, float* __restrict__ m3)
{
    __shared__ float sIn[PAD3];
    __shared__ float sM[PAD3];
    const int tid = threadIdx.x;
    const int tx = tid & 15, ty = tid >> 4;             // 16 x 8 spatial tile
    const int ocg = blockIdx.x >> 2;                    // 0..3 (16 oc each)
    const int ox0 = (blockIdx.x & 3) * 16, oy0 = blockIdx.y * 8;
    const int bz = blockIdx.z;
    const int half = bz / 10, rz = bz % 10;
    const int b = rz / 5, oz = rz % 5;
    const int iz0 = 2 * oz, iy0 = 2 * oy0 - 1, ix0 = 2 * ox0 - 1;  // z pad 0

    const bool needM = (half == 0) && (ocg == 0);
    if (needM) {
        for (int e = tid; e < NE3; e += 128) {
            const int ez = e / 561, rr = e % 561, ey = rr / 33, ex = rr % 33;
            const int iz = iz0 + ez, iy = iy0 + ey, ix = ix0 + ex;
            float mv = 0.f;
            if ((unsigned)iy < 128u && (unsigned)ix < 128u)  // iz always in [0,10]
                mv = m2[((b * 11 + iz) * 128 + iy) * 128 + ix];
            sM[e] = mv;
        }
        __syncthreads();
    }

    int   q14[14];
    float ok14[14];
#pragma unroll
    for (int j = 0; j < 14; ++j) {
        const int e = tid + j * 128;
        const int ez = e / 561, rr = e % 561, ey = rr / 33, ex = rr % 33;
        const int iz = iz0 + ez, iy = iy0 + ey, ix = ix0 + ex;
        const bool ok = (e < NE3) && (unsigned)iy < 128u && (unsigned)ix < 128u;
        q14[j] = ok ? (b * 5767168 + iz * 16384 + iy * 128 + ix) : 0;
        ok14[j] = ok ? 1.f : 0.f;
    }

    const int cin0 = half * 16;
    float pre[14];
#pragma unroll
    for (int j = 0; j < 14; ++j) pre[j] = h2[q14[j] + cin0 * 180224];

    float acc[16];
#pragma unroll
    for (int oc = 0; oc < 16; ++oc) acc[oc] = 0.f;

#pragma unroll 1
    for (int c = 0; c < 16; ++c) {
        const int cin = cin0 + c;
#pragma unroll
        for (int j = 0; j < 14; ++j)
            sIn[tid + j * 128] = pre[j] * ok14[j];
        __syncthreads();        // LDS published

        if (c < 15) {
#pragma unroll
            for (int j = 0; j < 14; ++j) pre[j] = h2[q14[j] + (cin + 1) * 180224];
        }

        const float* __restrict__ wq = wT3 + cin * 1728 + ocg * 16;  // block-uniform
#pragma unroll
        for (int kz = 0; kz < 3; ++kz)
#pragma unroll
            for (int ky = 0; ky < 3; ++ky)
#pragma unroll
                for (int kx = 0; kx < 3; ++kx) {
                    const int tap = (kz * 3 + ky) * 3 + kx;
                    const float vt = sIn[kz * 561 + (2 * ty + ky) * 33 + 2 * tx + kx];
#pragma unroll
                    for (int oc = 0; oc < 16; ++oc)
                        acc[oc] = fmaf(wq[tap * 64 + oc], vt, acc[oc]);
                }
        __syncthreads();        // LDS consumed
    }

    const int oy = oy0 + ty, ox = ox0 + tx;
    if (needM) {
        float msum = 0.f;
#pragma unroll
        for (int kz = 0; kz < 3; ++kz)
#pragma unroll
            for (int ky = 0; ky < 3; ++ky)
#pragma unroll
                for (int kx = 0; kx < 3; ++kx)
                    msum += sM[kz * 561 + (2 * ty + ky) * 33 + 2 * tx + kx];
        m3[(b * 5 + oz) * 4096 + oy * 64 + ox] = msum > 0.f ? 1.f : 0.f;
    }

    float* __restrict__ part = half ? p3b : p3a;
#pragma unroll
    for (int oc = 0; oc < 16; ++oc) {
        const int ocgl = ocg * 16 + oc;
        part[(((b * 64 + ocgl) * 5 + oz) * 64 + oy) * 64 + ox] = acc[oc];
    }
}

// ---------------- Layer 3 combine: h3 = relu(pa+pb+shift)*m3 ----------------
__global__ __launch_bounds__(256) void combine_l3(
    const float* __restrict__ p3a, const float* __restrict__ p3b,
    const float* __restrict__ m3, const float* __restrict__ shb,
    float* __restrict__ h3)
{
    const int idx = blockIdx.x * 256 + threadIdx.x;   // < 2,621,440
    const int b = idx / 1310720;
    const int r = idx - b * 1310720;
    const int oc = r / 20480;
    const int r2 = r - oc * 20480;
    const float mv = m3[b * 20480 + r2];
    h3[idx] = fmaxf(p3a[idx] + p3b[idx] + shb[32 + oc], 0.f) * mv;
}

// ---------------- Layer 4: conv 64->64, k(3,1,1), s(2,1,1), pad 0 ----------------
__global__ __launch_bounds__(256) __attribute__((amdgpu_waves_per_eu(4, 8)))
void conv_l4(
    const float* __restrict__ h3, const float* __restrict__ m3,
    const float* __restrict__ wT4, const float* __restrict__ shb,
    float* __restrict__ out)
{
    const int p = blockIdx.x * 256 + threadIdx.x;  // 0..4095 spatial
    const int bo = blockIdx.y;
    const int b = bo >> 4, od = (bo >> 3) & 1, ocg = bo & 7;

    const float msum = m3[(b * 5 + 2 * od + 0) * 4096 + p] +
                       m3[(b * 5 + 2 * od + 1) * 4096 + p] +
                       m3[(b * 5 + 2 * od + 2) * 4096 + p];
    const float mout = msum > 0.f ? 1.f : 0.f;

    float acc[8];
#pragma unroll
    for (int oc = 0; oc < 8; ++oc) acc[oc] = 0.f;

#pragma unroll 1
    for (int c = 0; c < 64; ++c) {
        const float v0 = h3[((b * 64 + c) * 5 + 2 * od + 0) * 4096 + p];
        const float v1 = h3[((b * 64 + c) * 5 + 2 * od + 1) * 4096 + p];
        const float v2 = h3[((b * 64 + c) * 5 + 2 * od + 2) * 4096 + p];
        const float* __restrict__ wq = wT4 + c * 192 + ocg * 8;  // block-uniform
#pragma unroll
        for (int oc = 0; oc < 8; ++oc) {
            acc[oc] = fmaf(wq[oc], v0,
                      fmaf(wq[64 + oc], v1,
                      fmaf(wq[128 + oc], v2, acc[oc])));
        }
    }

#pragma unroll
    for (int oc = 0; oc < 8; ++oc) {
        const int ocgl = ocg * 8 + oc;
        out[((b * 64 + ocgl) * 2 + od) * 4096 + p] =
            fmaxf(acc[oc] + shb[96 + ocgl], 0.f) * mout;
    }
}

extern "C" void kernel_launch(void* const* d_in, const int* in_sizes, int n_in,
                              void* d_out, int out_size, void* d_ws, size_t ws_size,
                              hipStream_t stream)
{
    const float* vf    = (const float*)d_in[0];
    const int*   coors = (const int*)d_in[1];
    // d_in[2] = batch_size (==2, hardcoded in geometry)
    const float* w1 = (const float*)d_in[3];
    const float* g1 = (const float*)d_in[4];
    const float* b1 = (const float*)d_in[5];
    const float* rm1 = (const float*)d_in[6];
    const float* rv1 = (const float*)d_in[7];
    const float* w2 = (const float*)d_in[8];
    const float* g2 = (const float*)d_in[9];
    const float* b2 = (const float*)d_in[10];
    const float* rm2 = (const float*)d_in[11];
    const float* rv2 = (const float*)d_in[12];
    const float* w3 = (const float*)d_in[13];
    const float* g3 = (const float*)d_in[14];
    const float* b3 = (const float*)d_in[15];
    const float* rm3 = (const float*)d_in[16];
    const float* rv3 = (const float*)d_in[17];
    const float* w4 = (const float*)d_in[18];
    const float* g4 = (const float*)d_in[19];
    const float* b4 = (const float*)d_in[20];
    const float* rm4 = (const float*)d_in[21];
    const float* rv4 = (const float*)d_in[22];

    const int NV = in_sizes[0] / 3;

    float* ws = (float*)d_ws;
    float* y1  = ws;                   // 44,040,192 f  (2,4,21,256,256,4) interleaved
    float* m1  = y1 + 44040192;        //  2,752,512 f  (2,21,256,256)
    float* h2  = m1 + 2752512;         // 11,534,336 f  (2,32,11,128,128)
    float* m2  = h2 + 11534336;        //    360,448 f  (2,11,128,128)
    float* h3  = m2 + 360448;          //  2,621,440 f  (2,64,5,64,64)
    float* m3  = h3 + 2621440;         //     40,960 f  (2,5,64,64)
    float* wT2 = m3 + 40960;           //     13,824 f
    float* wT3 = wT2 + 13824;          //     55,296 f
    float* wT4 = wT3 + 55296;          //     12,288 f
    float* shb = wT4 + 12288;          //        160 f
    // Partial buffers for conv_l3 overlay the y1 region (y1 dead after conv_l2).
    float* p3a = y1;                   //  2,621,440 f
    float* p3b = y1 + 2621440;         //  2,621,440 f

    // zero the scatter accumulator + mask (y1 and m1 are contiguous)
    hipMemsetAsync(y1, 0, (size_t)(44040192 + 2752512) * sizeof(float), stream);

    repack<<<319, 256, 0, stream>>>(w2, g2, b2, rm2, rv2, w3, g3, b3, rm3, rv3,
                                    w4, g4, b4, rm4, rv4, wT2, wT3, wT4, shb);
    scatter_l1<<<(NV * 16 + 255) / 256, 256, 0, stream>>>(vf, coors, NV, w1, y1, m1);
    conv_l2<<<dim3(4, 16, 22), 256, 0, stream>>>((const float4*)y1, m1, wT2, shb,
                                                 g1, b1, rm1, rv1, h2, m2);
    conv_l3<<<dim3(16, 8, 20), 128, 0, stream>>>(h2, m2, wT3, p3a, p3b, m3);
    combine_l3<<<10240, 256, 0, stream>>>(p3a, p3b, m3, shb, h3);
    conv_l4<<<dim3(16, 32), 256, 0, stream>>>(h3, m3, wT4, shb, (float*)d_out);
}